// Round 7
// baseline (219.763 us; speedup 1.0000x reference)
//
#include <hip/hip_runtime.h>
#include <math.h>

#define NQ     8
#define DIM    256
#define LAYERS 3
#define COUT   8
#define NB     32
#define OH     31
#define OW     31
#define NPATCH (NB*OH*OW)     // 30752
#define PT_BLK 1024           // patches per fused block (8 waves x 8 ptiles)
#define TILES  32             // 32 tiles x 8 ch = 256 blocks, XCD-bijective
#define PTOT   (TILES*PT_BLK) // 32768
#define NPTILE (PTOT/16)      // 2048 16-patch groups
#define NPAIR  72             // packed upper-tri (t,ks) pairs
#define MPACK  (NPAIR*64*8)   // 36864 halves per channel

typedef _Float16 f16x8 __attribute__((ext_vector_type(8)));
typedef _Float16 f16x4 __attribute__((ext_vector_type(4)));
typedef float    f32x4 __attribute__((ext_vector_type(4)));

__device__ __forceinline__ float2 cmul(float2 a, float2 b) {
    return make_float2(a.x*b.x - a.y*b.y, a.x*b.y + a.y*b.x);
}
__device__ __forceinline__ float2 cadd(float2 a, float2 b) {
    return make_float2(a.x + b.x, a.y + b.y);
}

// CNOT-ring permutation (verified round 1)
__device__ __forceinline__ int rho(int i) {
    #pragma unroll
    for (int q = 7; q >= 0; --q) {
        int t = (q + 1) & 7;
        if ((i >> (7 - q)) & 1) i ^= 1 << (7 - t);
    }
    return i;
}

// async global->LDS, 16B per lane, LDS dest = wave-uniform base + lane*16
__device__ __forceinline__ void gload_lds16(const _Float16* g, _Float16* l) {
    __builtin_amdgcn_global_load_lds(
        (const __attribute__((address_space(1))) void*)g,
        (__attribute__((address_space(3))) void*)l, 16, 0, 0);
}

// ---- 1. merged dispatch: blocks [0,2048) build W columns, [2048,4096) extract
__global__ __launch_bounds__(256) void wext(const float* __restrict__ w,
                                            _Float16* __restrict__ At,
                                            _Float16* __restrict__ Bt,
                                            const float* __restrict__ x,
                                            _Float16* __restrict__ sF) {
    __shared__ float2 g[96];
    __shared__ float2 vb[256];
    __shared__ _Float16 sT[16][264];

    if (blockIdx.x < 2048) {
        // ---------------- build_W: col j of U = P K2 P K1 P K0 --------------
        const int j  = blockIdx.x & 255;
        const int ch = blockIdx.x >> 8;
        const int i  = threadIdx.x;
        if (i < 24) {
            const float* wp = w + (ch*24 + i)*3;
            float phi = wp[0], th = wp[1], om = wp[2];
            float cth = cosf(th * 0.5f), sth = sinf(th * 0.5f);
            float a = 0.5f * (phi + om), b = 0.5f * (phi - om);
            float sa, ca, sb, cb;
            sincosf(a, &sa, &ca);
            sincosf(b, &sb, &cb);
            g[i*4+0] = make_float2( cth*ca, -cth*sa);
            g[i*4+1] = make_float2(-sth*cb, -sth*sb);
            g[i*4+2] = make_float2( sth*cb, -sth*sb);
            g[i*4+3] = make_float2( cth*ca,  cth*sa);
        }
        __syncthreads();

        float2 v = make_float2(1.f, 0.f);
        #pragma unroll
        for (int q = 0; q < 8; ++q) {
            int iq = (i >> (7 - q)) & 1, jq = (j >> (7 - q)) & 1;
            v = cmul(v, g[q*4 + iq*2 + jq]);
        }

        #pragma unroll
        for (int l = 1; l < 3; ++l) {
            vb[i] = v; __syncthreads();
            v = vb[rho(i)]; __syncthreads();
            #pragma unroll
            for (int q = 0; q < 2; ++q) {
                int bit = 1 << (7 - q);
                vb[i] = v; __syncthreads();
                float2 y = vb[i ^ bit]; __syncthreads();
                float2 m0 = (i & bit) ? g[(l*8+q)*4+3] : g[(l*8+q)*4+0];
                float2 m1 = (i & bit) ? g[(l*8+q)*4+2] : g[(l*8+q)*4+1];
                v = cadd(cmul(m0, v), cmul(m1, y));
            }
            #pragma unroll
            for (int q = 2; q < 8; ++q) {
                int bit = 1 << (7 - q);
                float2 y;
                y.x = __shfl_xor(v.x, bit, 64);
                y.y = __shfl_xor(v.y, bit, 64);
                float2 m0 = (i & bit) ? g[(l*8+q)*4+3] : g[(l*8+q)*4+0];
                float2 m1 = (i & bit) ? g[(l*8+q)*4+2] : g[(l*8+q)*4+1];
                v = cadd(cmul(m0, v), cmul(m1, y));
            }
        }
        vb[i] = v; __syncthreads();
        float2 a = vb[rho(i)];
        float sgn = (i & 128) ? -1.f : 1.f;
        size_t row = ((size_t)ch*256 + j) * 512;
        At[row + i]       = (_Float16)(sgn * a.x);
        At[row + 256 + i] = (_Float16)(sgn * a.y);
        Bt[row + i]       = (_Float16)a.x;
        Bt[row + 256 + i] = (_Float16)a.y;
    } else {
        // ---------------- extract -> fp16 in B-fragment order ---------------
        const int tb  = blockIdx.x - 2048;   // ptile 0..NPTILE-1
        const int tid = threadIdx.x;
        const int wv  = tid >> 6, lane = tid & 63;

        #pragma unroll
        for (int pp = 0; pp < 4; ++pp) {
            int pl = wv*4 + pp;
            int p  = tb*16 + pl;
            float2 v01 = make_float2(0.f,0.f), v23 = make_float2(0.f,0.f);
            if (p < NPATCH) {
                int b = p / (OH*OW); int r = p % (OH*OW);
                int oi = r / OW, oj = r % OW;
                int ci = lane >> 2, fi = lane & 3;
                const float* xb = x + (((size_t)(b*16 + ci))*64 + (oi*2 + fi))*64 + oj*2;
                v01 = *(const float2*)xb;
                v23 = *(const float2*)(xb + 2);
            }
            float ss = v01.x*v01.x + v01.y*v01.y + v23.x*v23.x + v23.y*v23.y;
            #pragma unroll
            for (int m = 1; m < 64; m <<= 1) ss += __shfl_xor(ss, m, 64);
            float inv = ss > 0.f ? 1.f / sqrtf(ss) : 0.f;
            f16x4 o;
            o[0] = (_Float16)(v01.x*inv); o[1] = (_Float16)(v01.y*inv);
            o[2] = (_Float16)(v23.x*inv); o[3] = (_Float16)(v23.y*inv);
            *(f16x4*)&sT[pl][lane*4] = o;
        }
        __syncthreads();

        #pragma unroll
        for (int e = 0; e < 2; ++e) {
            int vi = tid + e*256;            // 0..511
            int ks = vi >> 6, ln = vi & 63;
            int kq = ln >> 4, prow = ln & 15;
            f16x8 o = *(const f16x8*)&sT[prow][ks*32 + kq*8];
            ((f16x8*)sF)[(size_t)tb*512 + vi] = o;
        }
    }
}

// ---- 2. M' = upper-tri-doubled (A^T D A), K=512 fp16 MFMA, packed frag out -
__global__ __launch_bounds__(256) void build_Mp(const _Float16* __restrict__ At,
                                                const _Float16* __restrict__ Bt,
                                                _Float16* __restrict__ Mp) {
    const int ch = blockIdx.z;
    const int ti = blockIdx.y;                       // 0..15
    const int wv = threadIdx.x >> 6;
    const int jt = blockIdx.x * 4 + wv;              // 0..15
    const int jt0 = 2 * (ti >> 1);
    if (jt < jt0) return;
    const int lane = threadIdx.x & 63;
    const int c16 = lane & 15, kq = lane >> 4;
    const int OFFT[16] = {0,8,16,23,30,36,42,47,52,56,60,63,66,68,70,71};
    const int pidx = OFFT[ti] + (jt >> 1) - (ti >> 1);
    _Float16* Mc = Mp + (size_t)ch * MPACK;

    f32x4 acc = {0.f, 0.f, 0.f, 0.f};
    if (jt >= ti) {
        const _Float16* Ar = At + ((size_t)ch*256 + ti*16 + c16) * 512 + kq*8;
        const _Float16* Br = Bt + ((size_t)ch*256 + jt*16 + c16) * 512 + kq*8;
        #pragma unroll
        for (int kk = 0; kk < 16; ++kk) {
            f16x8 af = *(const f16x8*)(Ar + kk*32);
            f16x8 bf = *(const f16x8*)(Br + kk*32);
            acc = __builtin_amdgcn_mfma_f32_16x16x32_f16(af, bf, acc, 0, 0, 0);
        }
    }
    int wsel = (jt & 1) * 16 + c16;
    int kqp = wsel >> 3, jj = wsel & 7;
    #pragma unroll
    for (int reg = 0; reg < 4; ++reg) {
        int i_g = ti*16 + kq*4 + reg;
        int j_g = jt*16 + c16;
        float val = (jt >= ti) ? acc[reg] : 0.f;
        val *= (j_g > i_g) ? 2.f : ((j_g == i_g) ? 1.f : 0.f);
        Mc[(size_t)((pidx*64 + kqp*16 + (kq*4 + reg)) * 8 + jj)] = (_Float16)val;
    }
}

// ---- 3. fused MFMA quadform: out[p,c] = s_p^T M'_c s_p + bias[c] -----------
// 256 blocks (32 tiles x 8 ch), ALL co-resident (1 block/CU, 8 waves = 2/SIMD).
// 8 ptiles per wave: each M-fragment ds_read feeds 8 MFMAs.
// waves_per_eu(2,2): 256-VGPR budget (r3/r6 lesson: anything tighter spills).
__global__ __attribute__((amdgpu_flat_work_group_size(512,512), amdgpu_waves_per_eu(2,2)))
void fusedqf(const _Float16* __restrict__ sF,
             const _Float16* __restrict__ Mp,
             const float* __restrict__ bias,
             float* __restrict__ out) {
    extern __shared__ _Float16 Mlds[];      // 36864 halves = 72 KB
    const int id   = blockIdx.x;
    const int xcd  = id & 7;
    const int g    = id >> 3;               // 0..31
    const int c    = g >> 2;                // 0..7
    const int tile = (g & 3) * 8 + xcd;     // 0..31, XCD-pinned
    const int tid  = threadIdx.x;
    const int lane = tid & 63;
    const int wv   = tid >> 6;
    const int prow = lane & 15, kq = lane >> 4;
    const int tp0  = tile*64 + wv*8;        // base ptile; wave owns 8 ptiles
    const int OFFT[16] = {0,8,16,23,30,36,42,47,52,56,60,63,66,68,70,71};

    // async stage M' (9 x 1KB chunks per wave, zero VGPR cost)
    const _Float16* Msrc = Mp + (size_t)c * MPACK;
    #pragma unroll
    for (int it = 0; it < 9; ++it) {
        int off = (wv*9 + it) * 512;
        gload_lds16(Msrc + off + lane*8, Mlds + off);
    }

    // pass-A B fragments (ks 0..3), overlap with the LDS DMA
    f16x8 bfrag[8][4];
    #pragma unroll
    for (int pt = 0; pt < 8; ++pt) {
        const f16x8* src = (const f16x8*)sF + (size_t)(tp0 + pt)*512 + lane;
        #pragma unroll
        for (int ks = 0; ks < 4; ++ks)
            bfrag[pt][ks] = src[ks*64];
    }

    __syncthreads();   // drains DMA (vmcnt) + joins waves

    const _Float16* fold0 = sF + ((size_t)tp0*512 + (kq>>1)*16 + prow)*8 + (kq&1)*4;
    float o[8] = {0.f,0.f,0.f,0.f,0.f,0.f,0.f,0.f};

    // ---- pass A: t = 0..7, ks in [t>>1, 4) ----
    #pragma unroll
    for (int t = 0; t < 8; ++t) {
        f32x4 a[8];
        #pragma unroll
        for (int pt = 0; pt < 8; ++pt) a[pt] = (f32x4){0,0,0,0};
        #pragma unroll
        for (int ks = (t >> 1); ks < 4; ++ks) {
            int pidx = OFFT[t] + ks - (t >> 1);          // compile-time
            f16x8 m = *(const f16x8*)(Mlds + pidx*512 + lane*8);
            #pragma unroll
            for (int pt = 0; pt < 8; ++pt)
                a[pt] = __builtin_amdgcn_mfma_f32_16x16x32_f16(m, bfrag[pt][ks], a[pt], 0, 0, 0);
        }
        #pragma unroll
        for (int pt = 0; pt < 8; ++pt) {
            f16x4 sv = *(const f16x4*)(fold0 + pt*4096 + t*256);
            o[pt] += (float)sv[0]*a[pt][0] + (float)sv[1]*a[pt][1]
                   + (float)sv[2]*a[pt][2] + (float)sv[3]*a[pt][3];
        }
    }

    // ---- pass B: load ks 4..7 fragments, t = 0..15 ----
    #pragma unroll
    for (int pt = 0; pt < 8; ++pt) {
        const f16x8* src = (const f16x8*)sF + (size_t)(tp0 + pt)*512 + lane;
        #pragma unroll
        for (int ks = 0; ks < 4; ++ks)
            bfrag[pt][ks] = src[(ks+4)*64];
    }

    #pragma unroll
    for (int t = 0; t < 16; ++t) {
        const int ksmin = (t >> 1) < 4 ? 4 : (t >> 1);
        f32x4 a[8];
        #pragma unroll
        for (int pt = 0; pt < 8; ++pt) a[pt] = (f32x4){0,0,0,0};
        #pragma unroll
        for (int ks = ksmin; ks < 8; ++ks) {
            int pidx = OFFT[t] + ks - (t >> 1);          // compile-time
            f16x8 m = *(const f16x8*)(Mlds + pidx*512 + lane*8);
            #pragma unroll
            for (int pt = 0; pt < 8; ++pt)
                a[pt] = __builtin_amdgcn_mfma_f32_16x16x32_f16(m, bfrag[pt][ks-4], a[pt], 0, 0, 0);
        }
        #pragma unroll
        for (int pt = 0; pt < 8; ++pt) {
            f16x4 sv = *(const f16x4*)(fold0 + pt*4096 + t*256);
            o[pt] += (float)sv[0]*a[pt][0] + (float)sv[1]*a[pt][1]
                   + (float)sv[2]*a[pt][2] + (float)sv[3]*a[pt][3];
        }
    }

    float bc = bias[c];
    #pragma unroll
    for (int pt = 0; pt < 8; ++pt) {
        float v = o[pt];
        v += __shfl_xor(v, 16, 64);
        v += __shfl_xor(v, 32, 64);
        if (kq == 0) {
            int p = (tp0 + pt)*16 + prow;
            if (p < NPATCH) {
                int b = p / (OH*OW); int r2 = p % (OH*OW);
                int oi = r2 / OW, oj = r2 % OW;
                out[(((size_t)(b*COUT + c))*OH + oi)*OW + oj] = v + bc;
            }
        }
    }
}

extern "C" void kernel_launch(void* const* d_in, const int* in_sizes, int n_in,
                              void* d_out, int out_size, void* d_ws, size_t ws_size,
                              hipStream_t stream) {
    const float* x    = (const float*)d_in[0];
    const float* w    = (const float*)d_in[1];
    const float* bias = (const float*)d_in[2];
    float* out = (float*)d_out;

    const size_t OFF_AT  = 0;                       // 8*256*512*2 = 2,097,152
    const size_t OFF_BT  = OFF_AT + 2097152;        // 2,097,152
    const size_t OFF_MP  = OFF_BT + 2097152;        // 8*36864*2 = 589,824
    const size_t OFF_SF  = OFF_MP + 589824;         // 2048*512*16 = 16,777,216
    const size_t TOTAL   = OFF_SF + 16777216;
    if (ws_size < TOTAL) return;

    char* ws = (char*)d_ws;
    _Float16* At = (_Float16*)(ws + OFF_AT);
    _Float16* Bt = (_Float16*)(ws + OFF_BT);
    _Float16* Mp = (_Float16*)(ws + OFF_MP);
    _Float16* sF = (_Float16*)(ws + OFF_SF);

    wext<<<2048 + NPTILE, 256, 0, stream>>>(w, At, Bt, x, sF);
    build_Mp<<<dim3(4, 16, COUT), 256, 0, stream>>>(At, Bt, Mp);
    fusedqf<<<TILES*COUT, 512, MPACK*sizeof(_Float16), stream>>>(sF, Mp, bias, out);
}

// Round 8
// 97.884 us; speedup vs baseline: 2.2451x; 2.2451x over previous
//
#include <hip/hip_runtime.h>
#include <math.h>

#define NQ     8
#define DIM    256
#define LAYERS 3
#define COUT   8
#define NB     32
#define OH     31
#define OW     31
#define NPATCH (NB*OH*OW)     // 30752
#define PT_BLK 512
#define NTILE  64             // 64 tiles x 8 ch = 512 blocks, XCD-bijective
#define PTOT   (NTILE*PT_BLK) // 32768
#define NPTILE (PTOT/16)      // 2048 16-patch groups
#define NPAIR  72             // packed upper-tri (t,ks) pairs
#define MPACK  (NPAIR*64*8)   // 36864 halves per channel

typedef _Float16 f16x8 __attribute__((ext_vector_type(8)));
typedef _Float16 f16x4 __attribute__((ext_vector_type(4)));
typedef float    f32x4 __attribute__((ext_vector_type(4)));

__device__ __forceinline__ float2 cmul(float2 a, float2 b) {
    return make_float2(a.x*b.x - a.y*b.y, a.x*b.y + a.y*b.x);
}
__device__ __forceinline__ float2 cadd(float2 a, float2 b) {
    return make_float2(a.x + b.x, a.y + b.y);
}

// CNOT-ring permutation (verified round 1)
__device__ __forceinline__ int rho(int i) {
    #pragma unroll
    for (int q = 7; q >= 0; --q) {
        int t = (q + 1) & 7;
        if ((i >> (7 - q)) & 1) i ^= 1 << (7 - t);
    }
    return i;
}

// async global->LDS, 16B per lane, LDS dest = wave-uniform base + lane*16
__device__ __forceinline__ void gload_lds16(const _Float16* g, _Float16* l) {
    __builtin_amdgcn_global_load_lds(
        (const __attribute__((address_space(1))) void*)g,
        (__attribute__((address_space(3))) void*)l, 16, 0, 0);
}

// ---- 1. merged dispatch: blocks [0,2048) build W columns, [2048,4096) extract
__global__ __launch_bounds__(256) void wext(const float* __restrict__ w,
                                            _Float16* __restrict__ At,
                                            _Float16* __restrict__ Bt,
                                            const float* __restrict__ x,
                                            _Float16* __restrict__ sF) {
    __shared__ float2 g[96];
    __shared__ float2 vb[256];
    __shared__ _Float16 sT[16][264];

    if (blockIdx.x < 2048) {
        // ---------------- build_W: col j of U = P K2 P K1 P K0 --------------
        const int j  = blockIdx.x & 255;
        const int ch = blockIdx.x >> 8;
        const int i  = threadIdx.x;
        if (i < 24) {
            const float* wp = w + (ch*24 + i)*3;
            float phi = wp[0], th = wp[1], om = wp[2];
            float cth = cosf(th * 0.5f), sth = sinf(th * 0.5f);
            float a = 0.5f * (phi + om), b = 0.5f * (phi - om);
            float sa, ca, sb, cb;
            sincosf(a, &sa, &ca);
            sincosf(b, &sb, &cb);
            g[i*4+0] = make_float2( cth*ca, -cth*sa);
            g[i*4+1] = make_float2(-sth*cb, -sth*sb);
            g[i*4+2] = make_float2( sth*cb, -sth*sb);
            g[i*4+3] = make_float2( cth*ca,  cth*sa);
        }
        __syncthreads();

        float2 v = make_float2(1.f, 0.f);
        #pragma unroll
        for (int q = 0; q < 8; ++q) {
            int iq = (i >> (7 - q)) & 1, jq = (j >> (7 - q)) & 1;
            v = cmul(v, g[q*4 + iq*2 + jq]);
        }

        #pragma unroll
        for (int l = 1; l < 3; ++l) {
            vb[i] = v; __syncthreads();
            v = vb[rho(i)]; __syncthreads();
            #pragma unroll
            for (int q = 0; q < 2; ++q) {
                int bit = 1 << (7 - q);
                vb[i] = v; __syncthreads();
                float2 y = vb[i ^ bit]; __syncthreads();
                float2 m0 = (i & bit) ? g[(l*8+q)*4+3] : g[(l*8+q)*4+0];
                float2 m1 = (i & bit) ? g[(l*8+q)*4+2] : g[(l*8+q)*4+1];
                v = cadd(cmul(m0, v), cmul(m1, y));
            }
            #pragma unroll
            for (int q = 2; q < 8; ++q) {
                int bit = 1 << (7 - q);
                float2 y;
                y.x = __shfl_xor(v.x, bit, 64);
                y.y = __shfl_xor(v.y, bit, 64);
                float2 m0 = (i & bit) ? g[(l*8+q)*4+3] : g[(l*8+q)*4+0];
                float2 m1 = (i & bit) ? g[(l*8+q)*4+2] : g[(l*8+q)*4+1];
                v = cadd(cmul(m0, v), cmul(m1, y));
            }
        }
        vb[i] = v; __syncthreads();
        float2 a = vb[rho(i)];
        float sgn = (i & 128) ? -1.f : 1.f;
        size_t row = ((size_t)ch*256 + j) * 512;
        At[row + i]       = (_Float16)(sgn * a.x);
        At[row + 256 + i] = (_Float16)(sgn * a.y);
        Bt[row + i]       = (_Float16)a.x;
        Bt[row + 256 + i] = (_Float16)a.y;
    } else {
        // ---------------- extract -> fp16 in B-fragment order ---------------
        const int tb  = blockIdx.x - 2048;   // ptile 0..NPTILE-1
        const int tid = threadIdx.x;
        const int wv  = tid >> 6, lane = tid & 63;

        #pragma unroll
        for (int pp = 0; pp < 4; ++pp) {
            int pl = wv*4 + pp;
            int p  = tb*16 + pl;
            float2 v01 = make_float2(0.f,0.f), v23 = make_float2(0.f,0.f);
            if (p < NPATCH) {
                int b = p / (OH*OW); int r = p % (OH*OW);
                int oi = r / OW, oj = r % OW;
                int ci = lane >> 2, fi = lane & 3;
                const float* xb = x + (((size_t)(b*16 + ci))*64 + (oi*2 + fi))*64 + oj*2;
                v01 = *(const float2*)xb;
                v23 = *(const float2*)(xb + 2);
            }
            float ss = v01.x*v01.x + v01.y*v01.y + v23.x*v23.x + v23.y*v23.y;
            #pragma unroll
            for (int m = 1; m < 64; m <<= 1) ss += __shfl_xor(ss, m, 64);
            float inv = ss > 0.f ? 1.f / sqrtf(ss) : 0.f;
            f16x4 o;
            o[0] = (_Float16)(v01.x*inv); o[1] = (_Float16)(v01.y*inv);
            o[2] = (_Float16)(v23.x*inv); o[3] = (_Float16)(v23.y*inv);
            *(f16x4*)&sT[pl][lane*4] = o;
        }
        __syncthreads();

        #pragma unroll
        for (int e = 0; e < 2; ++e) {
            int vi = tid + e*256;            // 0..511
            int ks = vi >> 6, ln = vi & 63;
            int kq = ln >> 4, prow = ln & 15;
            f16x8 o = *(const f16x8*)&sT[prow][ks*32 + kq*8];
            ((f16x8*)sF)[(size_t)tb*512 + vi] = o;
        }
    }
}

// ---- 2. M' = upper-tri-doubled (A^T D A), K=512 fp16 MFMA, packed frag out -
__global__ __launch_bounds__(256) void build_Mp(const _Float16* __restrict__ At,
                                                const _Float16* __restrict__ Bt,
                                                _Float16* __restrict__ Mp) {
    const int ch = blockIdx.z;
    const int ti = blockIdx.y;                       // 0..15
    const int wv = threadIdx.x >> 6;
    const int jt = blockIdx.x * 4 + wv;              // 0..15
    const int jt0 = 2 * (ti >> 1);
    if (jt < jt0) return;
    const int lane = threadIdx.x & 63;
    const int c16 = lane & 15, kq = lane >> 4;
    const int OFFT[16] = {0,8,16,23,30,36,42,47,52,56,60,63,66,68,70,71};
    const int pidx = OFFT[ti] + (jt >> 1) - (ti >> 1);
    _Float16* Mc = Mp + (size_t)ch * MPACK;

    f32x4 acc = {0.f, 0.f, 0.f, 0.f};
    if (jt >= ti) {
        const _Float16* Ar = At + ((size_t)ch*256 + ti*16 + c16) * 512 + kq*8;
        const _Float16* Br = Bt + ((size_t)ch*256 + jt*16 + c16) * 512 + kq*8;
        #pragma unroll
        for (int kk = 0; kk < 16; ++kk) {
            f16x8 af = *(const f16x8*)(Ar + kk*32);
            f16x8 bf = *(const f16x8*)(Br + kk*32);
            acc = __builtin_amdgcn_mfma_f32_16x16x32_f16(af, bf, acc, 0, 0, 0);
        }
    }
    int wsel = (jt & 1) * 16 + c16;
    int kqp = wsel >> 3, jj = wsel & 7;
    #pragma unroll
    for (int reg = 0; reg < 4; ++reg) {
        int i_g = ti*16 + kq*4 + reg;
        int j_g = jt*16 + c16;
        float val = (jt >= ti) ? acc[reg] : 0.f;
        val *= (j_g > i_g) ? 2.f : ((j_g == i_g) ? 1.f : 0.f);
        Mc[(size_t)((pidx*64 + kqp*16 + (kq*4 + reg)) * 8 + jj)] = (_Float16)val;
    }
}

// ---- 3. fused MFMA quadform: out[p,c] = s_p^T M'_c s_p + bias[c] -----------
// 512 blocks XCD-pinned; 8 waves x 64 patches; M' (72KB) in LDS via async DMA.
// Two-pass ks split keeps the live set ~112 VGPRs: fits the observed 128-VGPR
// cap that waves_per_eu(2,2) + 8-wave blocks produces (r3/r6/r7 forensics).
// SINGLE DELTA vs r6-bench: waves_per_eu (4,4) -> (2,2).
__global__ __attribute__((amdgpu_flat_work_group_size(512,512), amdgpu_waves_per_eu(2,2)))
void fusedqf(const _Float16* __restrict__ sF,
             const _Float16* __restrict__ Mp,
             const float* __restrict__ bias,
             float* __restrict__ out) {
    extern __shared__ _Float16 Mlds[];      // 36864 halves = 72 KB
    const int id   = blockIdx.x;
    const int xcd  = id & 7;
    const int g    = id >> 3;
    const int c    = g >> 3;
    const int tile = (g & 7) * 8 + xcd;
    const int tid  = threadIdx.x;
    const int lane = tid & 63;
    const int wv   = tid >> 6;
    const int prow = lane & 15, kq = lane >> 4;
    const int tp0  = tile*32 + wv*4;        // base ptile (of 16 patches)
    const int OFFT[16] = {0,8,16,23,30,36,42,47,52,56,60,63,66,68,70,71};

    // async stage M' (9 x 1KB chunks per wave, zero VGPR cost)
    const _Float16* Msrc = Mp + (size_t)c * MPACK;
    #pragma unroll
    for (int it = 0; it < 9; ++it) {
        int off = (wv*9 + it) * 512;
        gload_lds16(Msrc + off + lane*8, Mlds + off);
    }

    // pass-A B fragments (ks 0..3), overlap with the LDS DMA
    f16x8 bfrag[4][4];
    #pragma unroll
    for (int pt = 0; pt < 4; ++pt) {
        const f16x8* src = (const f16x8*)sF + (size_t)(tp0 + pt)*512 + lane;
        #pragma unroll
        for (int ks = 0; ks < 4; ++ks)
            bfrag[pt][ks] = src[ks*64];
    }

    __syncthreads();   // drains DMA (vmcnt) + joins waves

    const _Float16* fold0 = sF + ((size_t)tp0*512 + (kq>>1)*16 + prow)*8 + (kq&1)*4;
    float o0 = 0.f, o1 = 0.f, o2 = 0.f, o3 = 0.f;

    // ---- pass A: t = 0..7, ks in [t>>1, 4) ----
    #pragma unroll
    for (int t = 0; t < 8; ++t) {
        f32x4 a0 = {0,0,0,0}, a1 = {0,0,0,0}, a2 = {0,0,0,0}, a3 = {0,0,0,0};
        #pragma unroll
        for (int ks = (t >> 1); ks < 4; ++ks) {
            int pidx = OFFT[t] + ks - (t >> 1);          // compile-time
            f16x8 a = *(const f16x8*)(Mlds + pidx*512 + lane*8);
            a0 = __builtin_amdgcn_mfma_f32_16x16x32_f16(a, bfrag[0][ks], a0, 0, 0, 0);
            a1 = __builtin_amdgcn_mfma_f32_16x16x32_f16(a, bfrag[1][ks], a1, 0, 0, 0);
            a2 = __builtin_amdgcn_mfma_f32_16x16x32_f16(a, bfrag[2][ks], a2, 0, 0, 0);
            a3 = __builtin_amdgcn_mfma_f32_16x16x32_f16(a, bfrag[3][ks], a3, 0, 0, 0);
        }
        f16x4 s0 = *(const f16x4*)(fold0 + 0*4096 + t*256);
        f16x4 s1 = *(const f16x4*)(fold0 + 1*4096 + t*256);
        f16x4 s2 = *(const f16x4*)(fold0 + 2*4096 + t*256);
        f16x4 s3 = *(const f16x4*)(fold0 + 3*4096 + t*256);
        o0 += (float)s0[0]*a0[0] + (float)s0[1]*a0[1] + (float)s0[2]*a0[2] + (float)s0[3]*a0[3];
        o1 += (float)s1[0]*a1[0] + (float)s1[1]*a1[1] + (float)s1[2]*a1[2] + (float)s1[3]*a1[3];
        o2 += (float)s2[0]*a2[0] + (float)s2[1]*a2[1] + (float)s2[2]*a2[2] + (float)s2[3]*a2[3];
        o3 += (float)s3[0]*a3[0] + (float)s3[1]*a3[1] + (float)s3[2]*a3[2] + (float)s3[3]*a3[3];
    }

    // ---- pass B: load ks 4..7 fragments, t = 0..15 ----
    #pragma unroll
    for (int pt = 0; pt < 4; ++pt) {
        const f16x8* src = (const f16x8*)sF + (size_t)(tp0 + pt)*512 + lane;
        #pragma unroll
        for (int ks = 0; ks < 4; ++ks)
            bfrag[pt][ks] = src[(ks+4)*64];
    }

    #pragma unroll
    for (int t = 0; t < 16; ++t) {
        const int ksmin = (t >> 1) < 4 ? 4 : (t >> 1);
        f32x4 a0 = {0,0,0,0}, a1 = {0,0,0,0}, a2 = {0,0,0,0}, a3 = {0,0,0,0};
        #pragma unroll
        for (int ks = ksmin; ks < 8; ++ks) {
            int pidx = OFFT[t] + ks - (t >> 1);          // compile-time
            f16x8 a = *(const f16x8*)(Mlds + pidx*512 + lane*8);
            a0 = __builtin_amdgcn_mfma_f32_16x16x32_f16(a, bfrag[0][ks-4], a0, 0, 0, 0);
            a1 = __builtin_amdgcn_mfma_f32_16x16x32_f16(a, bfrag[1][ks-4], a1, 0, 0, 0);
            a2 = __builtin_amdgcn_mfma_f32_16x16x32_f16(a, bfrag[2][ks-4], a2, 0, 0, 0);
            a3 = __builtin_amdgcn_mfma_f32_16x16x32_f16(a, bfrag[3][ks-4], a3, 0, 0, 0);
        }
        f16x4 s0 = *(const f16x4*)(fold0 + 0*4096 + t*256);
        f16x4 s1 = *(const f16x4*)(fold0 + 1*4096 + t*256);
        f16x4 s2 = *(const f16x4*)(fold0 + 2*4096 + t*256);
        f16x4 s3 = *(const f16x4*)(fold0 + 3*4096 + t*256);
        o0 += (float)s0[0]*a0[0] + (float)s0[1]*a0[1] + (float)s0[2]*a0[2] + (float)s0[3]*a0[3];
        o1 += (float)s1[0]*a1[0] + (float)s1[1]*a1[1] + (float)s1[2]*a1[2] + (float)s1[3]*a1[3];
        o2 += (float)s2[0]*a2[0] + (float)s2[1]*a2[1] + (float)s2[2]*a2[2] + (float)s2[3]*a2[3];
        o3 += (float)s3[0]*a3[0] + (float)s3[1]*a3[1] + (float)s3[2]*a3[2] + (float)s3[3]*a3[3];
    }

    float ov[4] = {o0, o1, o2, o3};
    float bc = bias[c];
    #pragma unroll
    for (int pt = 0; pt < 4; ++pt) {
        float v = ov[pt];
        v += __shfl_xor(v, 16, 64);
        v += __shfl_xor(v, 32, 64);
        if (kq == 0) {
            int p = (tp0 + pt)*16 + prow;
            if (p < NPATCH) {
                int b = p / (OH*OW); int r2 = p % (OH*OW);
                int oi = r2 / OW, oj = r2 % OW;
                out[(((size_t)(b*COUT + c))*OH + oi)*OW + oj] = v + bc;
            }
        }
    }
}

extern "C" void kernel_launch(void* const* d_in, const int* in_sizes, int n_in,
                              void* d_out, int out_size, void* d_ws, size_t ws_size,
                              hipStream_t stream) {
    const float* x    = (const float*)d_in[0];
    const float* w    = (const float*)d_in[1];
    const float* bias = (const float*)d_in[2];
    float* out = (float*)d_out;

    const size_t OFF_AT  = 0;                       // 8*256*512*2 = 2,097,152
    const size_t OFF_BT  = OFF_AT + 2097152;        // 2,097,152
    const size_t OFF_MP  = OFF_BT + 2097152;        // 8*36864*2 = 589,824
    const size_t OFF_SF  = OFF_MP + 589824;         // 2048*512*16 = 16,777,216
    const size_t TOTAL   = OFF_SF + 16777216;
    if (ws_size < TOTAL) return;

    char* ws = (char*)d_ws;
    _Float16* At = (_Float16*)(ws + OFF_AT);
    _Float16* Bt = (_Float16*)(ws + OFF_BT);
    _Float16* Mp = (_Float16*)(ws + OFF_MP);
    _Float16* sF = (_Float16*)(ws + OFF_SF);

    wext<<<2048 + NPTILE, 256, 0, stream>>>(w, At, Bt, x, sF);
    build_Mp<<<dim3(4, 16, COUT), 256, 0, stream>>>(At, Bt, Mp);
    fusedqf<<<NTILE*COUT, 512, MPACK*sizeof(_Float16), stream>>>(sF, Mp, bias, out);
}

// Round 9
// 60.893 us; speedup vs baseline: 3.6090x; 1.6075x over previous
//
#include <hip/hip_runtime.h>
#include <math.h>

#define NQ     8
#define DIM    256
#define LAYERS 3
#define COUT   8
#define NB     32
#define OH     31
#define OW     31
#define NPATCH (NB*OH*OW)     // 30752
#define PT_BLK 512
#define NTILE  64             // 64 tiles x 8 ch = 512 blocks, XCD-bijective
#define PTOT   (NTILE*PT_BLK) // 32768
#define NPTILE (PTOT/16)      // 2048 16-patch groups
#define NPAIR  72             // packed upper-tri (t,ks) pairs
#define MPACK  (NPAIR*64*8)   // 36864 halves per channel

typedef _Float16 f16x8 __attribute__((ext_vector_type(8)));
typedef _Float16 f16x4 __attribute__((ext_vector_type(4)));
typedef float    f32x4 __attribute__((ext_vector_type(4)));

__device__ __forceinline__ float2 cmul(float2 a, float2 b) {
    return make_float2(a.x*b.x - a.y*b.y, a.x*b.y + a.y*b.x);
}
__device__ __forceinline__ float2 cadd(float2 a, float2 b) {
    return make_float2(a.x + b.x, a.y + b.y);
}

// CNOT-ring permutation (verified round 1)
__device__ __forceinline__ int rho(int i) {
    #pragma unroll
    for (int q = 7; q >= 0; --q) {
        int t = (q + 1) & 7;
        if ((i >> (7 - q)) & 1) i ^= 1 << (7 - t);
    }
    return i;
}

// async global->LDS, 16B per lane, LDS dest = wave-uniform base + lane*16
__device__ __forceinline__ void gload_lds16(const _Float16* g, _Float16* l) {
    __builtin_amdgcn_global_load_lds(
        (const __attribute__((address_space(1))) void*)g,
        (__attribute__((address_space(3))) void*)l, 16, 0, 0);
}

// ---- 1. merged dispatch: blocks [0,2048) build W columns, [2048,4096) extract
__global__ __launch_bounds__(256) void wext(const float* __restrict__ w,
                                            _Float16* __restrict__ At,
                                            _Float16* __restrict__ Bt,
                                            const float* __restrict__ x,
                                            _Float16* __restrict__ sF) {
    __shared__ float2 g[96];
    __shared__ float2 vb[256];
    __shared__ _Float16 sT[16][264];

    if (blockIdx.x < 2048) {
        // ---------------- build_W: col j of U = P K2 P K1 P K0 --------------
        const int j  = blockIdx.x & 255;
        const int ch = blockIdx.x >> 8;
        const int i  = threadIdx.x;
        if (i < 24) {
            const float* wp = w + (ch*24 + i)*3;
            float phi = wp[0], th = wp[1], om = wp[2];
            float cth = cosf(th * 0.5f), sth = sinf(th * 0.5f);
            float a = 0.5f * (phi + om), b = 0.5f * (phi - om);
            float sa, ca, sb, cb;
            sincosf(a, &sa, &ca);
            sincosf(b, &sb, &cb);
            g[i*4+0] = make_float2( cth*ca, -cth*sa);
            g[i*4+1] = make_float2(-sth*cb, -sth*sb);
            g[i*4+2] = make_float2( sth*cb, -sth*sb);
            g[i*4+3] = make_float2( cth*ca,  cth*sa);
        }
        __syncthreads();

        float2 v = make_float2(1.f, 0.f);
        #pragma unroll
        for (int q = 0; q < 8; ++q) {
            int iq = (i >> (7 - q)) & 1, jq = (j >> (7 - q)) & 1;
            v = cmul(v, g[q*4 + iq*2 + jq]);
        }

        #pragma unroll
        for (int l = 1; l < 3; ++l) {
            vb[i] = v; __syncthreads();
            v = vb[rho(i)]; __syncthreads();
            #pragma unroll
            for (int q = 0; q < 2; ++q) {
                int bit = 1 << (7 - q);
                vb[i] = v; __syncthreads();
                float2 y = vb[i ^ bit]; __syncthreads();
                float2 m0 = (i & bit) ? g[(l*8+q)*4+3] : g[(l*8+q)*4+0];
                float2 m1 = (i & bit) ? g[(l*8+q)*4+2] : g[(l*8+q)*4+1];
                v = cadd(cmul(m0, v), cmul(m1, y));
            }
            #pragma unroll
            for (int q = 2; q < 8; ++q) {
                int bit = 1 << (7 - q);
                float2 y;
                y.x = __shfl_xor(v.x, bit, 64);
                y.y = __shfl_xor(v.y, bit, 64);
                float2 m0 = (i & bit) ? g[(l*8+q)*4+3] : g[(l*8+q)*4+0];
                float2 m1 = (i & bit) ? g[(l*8+q)*4+2] : g[(l*8+q)*4+1];
                v = cadd(cmul(m0, v), cmul(m1, y));
            }
        }
        vb[i] = v; __syncthreads();
        float2 a = vb[rho(i)];
        float sgn = (i & 128) ? -1.f : 1.f;
        size_t row = ((size_t)ch*256 + j) * 512;
        At[row + i]       = (_Float16)(sgn * a.x);
        At[row + 256 + i] = (_Float16)(sgn * a.y);
        Bt[row + i]       = (_Float16)a.x;
        Bt[row + 256 + i] = (_Float16)a.y;
    } else {
        // ---------------- extract -> fp16 in B-fragment order ---------------
        const int tb  = blockIdx.x - 2048;   // ptile 0..NPTILE-1
        const int tid = threadIdx.x;
        const int wv  = tid >> 6, lane = tid & 63;

        #pragma unroll
        for (int pp = 0; pp < 4; ++pp) {
            int pl = wv*4 + pp;
            int p  = tb*16 + pl;
            float2 v01 = make_float2(0.f,0.f), v23 = make_float2(0.f,0.f);
            if (p < NPATCH) {
                int b = p / (OH*OW); int r = p % (OH*OW);
                int oi = r / OW, oj = r % OW;
                int ci = lane >> 2, fi = lane & 3;
                const float* xb = x + (((size_t)(b*16 + ci))*64 + (oi*2 + fi))*64 + oj*2;
                v01 = *(const float2*)xb;
                v23 = *(const float2*)(xb + 2);
            }
            float ss = v01.x*v01.x + v01.y*v01.y + v23.x*v23.x + v23.y*v23.y;
            #pragma unroll
            for (int m = 1; m < 64; m <<= 1) ss += __shfl_xor(ss, m, 64);
            float inv = ss > 0.f ? 1.f / sqrtf(ss) : 0.f;
            f16x4 o;
            o[0] = (_Float16)(v01.x*inv); o[1] = (_Float16)(v01.y*inv);
            o[2] = (_Float16)(v23.x*inv); o[3] = (_Float16)(v23.y*inv);
            *(f16x4*)&sT[pl][lane*4] = o;
        }
        __syncthreads();

        #pragma unroll
        for (int e = 0; e < 2; ++e) {
            int vi = tid + e*256;            // 0..511
            int ks = vi >> 6, ln = vi & 63;
            int kq = ln >> 4, prow = ln & 15;
            f16x8 o = *(const f16x8*)&sT[prow][ks*32 + kq*8];
            ((f16x8*)sF)[(size_t)tb*512 + vi] = o;
        }
    }
}

// ---- 2. M' = upper-tri-doubled (A^T D A), K=512 fp16 MFMA, packed frag out -
__global__ __launch_bounds__(256) void build_Mp(const _Float16* __restrict__ At,
                                                const _Float16* __restrict__ Bt,
                                                _Float16* __restrict__ Mp) {
    const int ch = blockIdx.z;
    const int ti = blockIdx.y;                       // 0..15
    const int wv = threadIdx.x >> 6;
    const int jt = blockIdx.x * 4 + wv;              // 0..15
    const int jt0 = 2 * (ti >> 1);
    if (jt < jt0) return;
    const int lane = threadIdx.x & 63;
    const int c16 = lane & 15, kq = lane >> 4;
    // OFFT via formula (avoid runtime-indexed local array -> scratch):
    const int h = ti >> 1;
    const int offt = 8*ti - (h*(h-1) + h*(ti & 1));
    const int pidx = offt + (jt >> 1) - h;
    _Float16* Mc = Mp + (size_t)ch * MPACK;

    f32x4 acc = {0.f, 0.f, 0.f, 0.f};
    if (jt >= ti) {
        const _Float16* Ar = At + ((size_t)ch*256 + ti*16 + c16) * 512 + kq*8;
        const _Float16* Br = Bt + ((size_t)ch*256 + jt*16 + c16) * 512 + kq*8;
        #pragma unroll
        for (int kk = 0; kk < 16; ++kk) {
            f16x8 af = *(const f16x8*)(Ar + kk*32);
            f16x8 bf = *(const f16x8*)(Br + kk*32);
            acc = __builtin_amdgcn_mfma_f32_16x16x32_f16(af, bf, acc, 0, 0, 0);
        }
    }
    int wsel = (jt & 1) * 16 + c16;
    int kqp = wsel >> 3, jj = wsel & 7;
    #pragma unroll
    for (int reg = 0; reg < 4; ++reg) {
        int i_g = ti*16 + kq*4 + reg;
        int j_g = jt*16 + c16;
        float val = (jt >= ti) ? acc[reg] : 0.f;
        val *= (j_g > i_g) ? 2.f : ((j_g == i_g) ? 1.f : 0.f);
        Mc[(size_t)((pidx*64 + kqp*16 + (kq*4 + reg)) * 8 + jj)] = (_Float16)val;
    }
}

// ---- 3. fused MFMA quadform: out[p,c] = s_p^T M'_c s_p + bias[c] -----------
// 512 blocks XCD-pinned; 8 waves x 64 patches; M' (72KB) in LDS via async DMA.
// RUNTIME t-loops (#pragma unroll 1): keeps live set ~110 VGPR under the 128
// cap that (2,2)+8-wave blocks imposes (r8 forensics: full unroll -> scheduler
// hoisting -> spill at the cap). pidx = running packed-pair counter (uniform).
__global__ __attribute__((amdgpu_flat_work_group_size(512,512), amdgpu_waves_per_eu(2,2)))
void fusedqf(const _Float16* __restrict__ sF,
             const _Float16* __restrict__ Mp,
             const float* __restrict__ bias,
             float* __restrict__ out) {
    extern __shared__ _Float16 Mlds[];      // 36864 halves = 72 KB
    const int id   = blockIdx.x;
    const int xcd  = id & 7;
    const int g    = id >> 3;
    const int c    = g >> 3;
    const int tile = (g & 7) * 8 + xcd;
    const int tid  = threadIdx.x;
    const int lane = tid & 63;
    const int wv   = tid >> 6;
    const int prow = lane & 15, kq = lane >> 4;
    const int tp0  = tile*32 + wv*4;        // base ptile (of 16 patches)

    // async stage M' (9 x 1KB chunks per wave, zero VGPR cost)
    const _Float16* Msrc = Mp + (size_t)c * MPACK;
    #pragma unroll
    for (int it = 0; it < 9; ++it) {
        int off = (wv*9 + it) * 512;
        gload_lds16(Msrc + off + lane*8, Mlds + off);
    }

    // pass-A B fragments (ks 0..3), overlap with the LDS DMA
    f16x8 bfrag[4][4];
    #pragma unroll
    for (int pt = 0; pt < 4; ++pt) {
        const f16x8* src = (const f16x8*)sF + (size_t)(tp0 + pt)*512 + lane;
        #pragma unroll
        for (int ks = 0; ks < 4; ++ks)
            bfrag[pt][ks] = src[ks*64];
    }

    __syncthreads();   // drains DMA (vmcnt) + joins waves

    const _Float16* fold0 = sF + ((size_t)tp0*512 + (kq>>1)*16 + prow)*8 + (kq&1)*4;
    float o0 = 0.f, o1 = 0.f, o2 = 0.f, o3 = 0.f;
    int pidx = 0;

    f16x4 svn[4];
    #pragma unroll
    for (int pt = 0; pt < 4; ++pt)
        svn[pt] = *(const f16x4*)(fold0 + pt*4096);

    // ---- pass A: t = 0..7 (runtime), ks in [t>>1, 4) ----
    #pragma unroll 1
    for (int t = 0; t < 8; ++t) {
        const int h = t >> 1;
        f16x4 svc[4];
        #pragma unroll
        for (int pt = 0; pt < 4; ++pt) svc[pt] = svn[pt];
        #pragma unroll
        for (int pt = 0; pt < 4; ++pt)
            svn[pt] = *(const f16x4*)(fold0 + pt*4096 + (t+1)*256);  // t=7 reads pass-B t=0? no: t+1=8 valid (t*256<4096)

        f32x4 a0 = {0,0,0,0}, a1 = {0,0,0,0}, a2 = {0,0,0,0}, a3 = {0,0,0,0};
        #pragma unroll
        for (int ks = 0; ks < 4; ++ks) {
            if (ks >= h) {                               // wave-uniform
                f16x8 m = *(const f16x8*)(Mlds + (size_t)pidx*512 + lane*8);
                a0 = __builtin_amdgcn_mfma_f32_16x16x32_f16(m, bfrag[0][ks], a0, 0, 0, 0);
                a1 = __builtin_amdgcn_mfma_f32_16x16x32_f16(m, bfrag[1][ks], a1, 0, 0, 0);
                a2 = __builtin_amdgcn_mfma_f32_16x16x32_f16(m, bfrag[2][ks], a2, 0, 0, 0);
                a3 = __builtin_amdgcn_mfma_f32_16x16x32_f16(m, bfrag[3][ks], a3, 0, 0, 0);
                ++pidx;
            }
        }
        pidx += 4;   // skip this t's pass-B pairs (ks 4..7)

        o0 += (float)svc[0][0]*a0[0] + (float)svc[0][1]*a0[1] + (float)svc[0][2]*a0[2] + (float)svc[0][3]*a0[3];
        o1 += (float)svc[1][0]*a1[0] + (float)svc[1][1]*a1[1] + (float)svc[1][2]*a1[2] + (float)svc[1][3]*a1[3];
        o2 += (float)svc[2][0]*a2[0] + (float)svc[2][1]*a2[1] + (float)svc[2][2]*a2[2] + (float)svc[2][3]*a2[3];
        o3 += (float)svc[3][0]*a3[0] + (float)svc[3][1]*a3[1] + (float)svc[3][2]*a3[2] + (float)svc[3][3]*a3[3];
    }

    // ---- pass B: load ks 4..7 fragments, t = 0..15 (runtime) ----
    #pragma unroll
    for (int pt = 0; pt < 4; ++pt) {
        const f16x8* src = (const f16x8*)sF + (size_t)(tp0 + pt)*512 + lane;
        #pragma unroll
        for (int ks = 0; ks < 4; ++ks)
            bfrag[pt][ks] = src[(ks+4)*64];
    }

    pidx = 0;
    #pragma unroll
    for (int pt = 0; pt < 4; ++pt)
        svn[pt] = *(const f16x4*)(fold0 + pt*4096);

    #pragma unroll 1
    for (int t = 0; t < 16; ++t) {
        const int h = t >> 1;
        pidx += (h < 4) ? (4 - h) : 0;   // skip this t's pass-A pairs
        f16x4 svc[4];
        #pragma unroll
        for (int pt = 0; pt < 4; ++pt) svc[pt] = svn[pt];
        if (t < 15) {
            #pragma unroll
            for (int pt = 0; pt < 4; ++pt)
                svn[pt] = *(const f16x4*)(fold0 + pt*4096 + (t+1)*256);
        }

        f32x4 a0 = {0,0,0,0}, a1 = {0,0,0,0}, a2 = {0,0,0,0}, a3 = {0,0,0,0};
        #pragma unroll
        for (int ks = 4; ks < 8; ++ks) {
            if (ks >= h) {                               // wave-uniform
                f16x8 m = *(const f16x8*)(Mlds + (size_t)pidx*512 + lane*8);
                a0 = __builtin_amdgcn_mfma_f32_16x16x32_f16(m, bfrag[0][ks-4], a0, 0, 0, 0);
                a1 = __builtin_amdgcn_mfma_f32_16x16x32_f16(m, bfrag[1][ks-4], a1, 0, 0, 0);
                a2 = __builtin_amdgcn_mfma_f32_16x16x32_f16(m, bfrag[2][ks-4], a2, 0, 0, 0);
                a3 = __builtin_amdgcn_mfma_f32_16x16x32_f16(m, bfrag[3][ks-4], a3, 0, 0, 0);
                ++pidx;
            }
        }

        o0 += (float)svc[0][0]*a0[0] + (float)svc[0][1]*a0[1] + (float)svc[0][2]*a0[2] + (float)svc[0][3]*a0[3];
        o1 += (float)svc[1][0]*a1[0] + (float)svc[1][1]*a1[1] + (float)svc[1][2]*a1[2] + (float)svc[1][3]*a1[3];
        o2 += (float)svc[2][0]*a2[0] + (float)svc[2][1]*a2[1] + (float)svc[2][2]*a2[2] + (float)svc[2][3]*a2[3];
        o3 += (float)svc[3][0]*a3[0] + (float)svc[3][1]*a3[1] + (float)svc[3][2]*a3[2] + (float)svc[3][3]*a3[3];
    }

    float ov[4] = {o0, o1, o2, o3};
    float bc = bias[c];
    #pragma unroll
    for (int pt = 0; pt < 4; ++pt) {
        float v = ov[pt];
        v += __shfl_xor(v, 16, 64);
        v += __shfl_xor(v, 32, 64);
        if (kq == 0) {
            int p = (tp0 + pt)*16 + prow;
            if (p < NPATCH) {
                int b = p / (OH*OW); int r2 = p % (OH*OW);
                int oi = r2 / OW, oj = r2 % OW;
                out[(((size_t)(b*COUT + c))*OH + oi)*OW + oj] = v + bc;
            }
        }
    }
}

extern "C" void kernel_launch(void* const* d_in, const int* in_sizes, int n_in,
                              void* d_out, int out_size, void* d_ws, size_t ws_size,
                              hipStream_t stream) {
    const float* x    = (const float*)d_in[0];
    const float* w    = (const float*)d_in[1];
    const float* bias = (const float*)d_in[2];
    float* out = (float*)d_out;

    const size_t OFF_AT  = 0;                       // 8*256*512*2 = 2,097,152
    const size_t OFF_BT  = OFF_AT + 2097152;        // 2,097,152
    const size_t OFF_MP  = OFF_BT + 2097152;        // 8*36864*2 = 589,824
    const size_t OFF_SF  = OFF_MP + 589824;         // 2048*512*16 = 16,777,216
    const size_t TOTAL   = OFF_SF + 16777216;
    if (ws_size < TOTAL) return;

    char* ws = (char*)d_ws;
    _Float16* At = (_Float16*)(ws + OFF_AT);
    _Float16* Bt = (_Float16*)(ws + OFF_BT);
    _Float16* Mp = (_Float16*)(ws + OFF_MP);
    _Float16* sF = (_Float16*)(ws + OFF_SF);

    wext<<<2048 + NPTILE, 256, 0, stream>>>(w, At, Bt, x, sF);
    build_Mp<<<dim3(4, 16, COUT), 256, 0, stream>>>(At, Bt, Mp);
    fusedqf<<<NTILE*COUT, 512, MPACK*sizeof(_Float16), stream>>>(sF, Mp, bias, out);
}

// Round 11
// 58.629 us; speedup vs baseline: 3.7484x; 1.0386x over previous
//
#include <hip/hip_runtime.h>
#include <math.h>

#define NQ     8
#define DIM    256
#define LAYERS 3
#define COUT   8
#define NB     32
#define OH     31
#define OW     31
#define NPATCH (NB*OH*OW)     // 30752
#define PT_BLK 512
#define NTILE  64             // 64 tiles x 8 ch = 512 blocks, XCD-bijective
#define PTOT   (NTILE*PT_BLK) // 32768
#define NPTILE (PTOT/16)      // 2048 16-patch groups
#define NPAIR  72             // packed upper-tri (t,ks) pairs
#define MPACK  (NPAIR*64*8)   // 36864 halves per channel

typedef _Float16 f16x8 __attribute__((ext_vector_type(8)));
typedef _Float16 f16x4 __attribute__((ext_vector_type(4)));
typedef _Float16 f16x2 __attribute__((ext_vector_type(2)));
typedef __fp16   h16x2 __attribute__((ext_vector_type(2)));
typedef float    f32x4 __attribute__((ext_vector_type(4)));

__device__ __forceinline__ float2 cmul(float2 a, float2 b) {
    return make_float2(a.x*b.x - a.y*b.y, a.x*b.y + a.y*b.x);
}
__device__ __forceinline__ float2 cadd(float2 a, float2 b) {
    return make_float2(a.x + b.x, a.y + b.y);
}

// CNOT-ring permutation (verified round 1)
__device__ __forceinline__ int rho(int i) {
    #pragma unroll
    for (int q = 7; q >= 0; --q) {
        int t = (q + 1) & 7;
        if ((i >> (7 - q)) & 1) i ^= 1 << (7 - t);
    }
    return i;
}

// async global->LDS, 16B per lane, LDS dest = wave-uniform base + lane*16
__device__ __forceinline__ void gload_lds16(const _Float16* g, _Float16* l) {
    __builtin_amdgcn_global_load_lds(
        (const __attribute__((address_space(1))) void*)g,
        (__attribute__((address_space(3))) void*)l, 16, 0, 0);
}

// fold: o += dot(sv, a[0..3]) via packed f16 dot2 (halves the fold VALU).
// cvt_pkrtz/fdot2 use __fp16x2; bit_cast from _Float16x2 is a no-op.
__device__ __forceinline__ float fold4(f16x4 sv, f32x4 a, float o) {
    h16x2 s01 = __builtin_bit_cast(h16x2, (f16x2)__builtin_shufflevector(sv, sv, 0, 1));
    h16x2 s23 = __builtin_bit_cast(h16x2, (f16x2)__builtin_shufflevector(sv, sv, 2, 3));
    h16x2 y01 = __builtin_amdgcn_cvt_pkrtz(a[0], a[1]);
    h16x2 y23 = __builtin_amdgcn_cvt_pkrtz(a[2], a[3]);
    o = __builtin_amdgcn_fdot2(s01, y01, o, false);
    o = __builtin_amdgcn_fdot2(s23, y23, o, false);
    return o;
}

// ---- 1. merged dispatch: blocks [0,2048) build W columns, [2048,4096) extract
__global__ __launch_bounds__(256) void wext(const float* __restrict__ w,
                                            _Float16* __restrict__ At,
                                            _Float16* __restrict__ Bt,
                                            const float* __restrict__ x,
                                            _Float16* __restrict__ sF) {
    __shared__ float2 g[96];
    __shared__ float2 vb[256];
    __shared__ _Float16 sT[16][264];

    if (blockIdx.x < 2048) {
        // ---------------- build_W: col j of U = P K2 P K1 P K0 --------------
        const int j  = blockIdx.x & 255;
        const int ch = blockIdx.x >> 8;
        const int i  = threadIdx.x;
        if (i < 24) {
            const float* wp = w + (ch*24 + i)*3;
            float phi = wp[0], th = wp[1], om = wp[2];
            float cth = cosf(th * 0.5f), sth = sinf(th * 0.5f);
            float a = 0.5f * (phi + om), b = 0.5f * (phi - om);
            float sa, ca, sb, cb;
            sincosf(a, &sa, &ca);
            sincosf(b, &sb, &cb);
            g[i*4+0] = make_float2( cth*ca, -cth*sa);
            g[i*4+1] = make_float2(-sth*cb, -sth*sb);
            g[i*4+2] = make_float2( sth*cb, -sth*sb);
            g[i*4+3] = make_float2( cth*ca,  cth*sa);
        }
        __syncthreads();

        float2 v = make_float2(1.f, 0.f);
        #pragma unroll
        for (int q = 0; q < 8; ++q) {
            int iq = (i >> (7 - q)) & 1, jq = (j >> (7 - q)) & 1;
            v = cmul(v, g[q*4 + iq*2 + jq]);
        }

        #pragma unroll
        for (int l = 1; l < 3; ++l) {
            vb[i] = v; __syncthreads();
            v = vb[rho(i)]; __syncthreads();
            #pragma unroll
            for (int q = 0; q < 2; ++q) {
                int bit = 1 << (7 - q);
                vb[i] = v; __syncthreads();
                float2 y = vb[i ^ bit]; __syncthreads();
                float2 m0 = (i & bit) ? g[(l*8+q)*4+3] : g[(l*8+q)*4+0];
                float2 m1 = (i & bit) ? g[(l*8+q)*4+2] : g[(l*8+q)*4+1];
                v = cadd(cmul(m0, v), cmul(m1, y));
            }
            #pragma unroll
            for (int q = 2; q < 8; ++q) {
                int bit = 1 << (7 - q);
                float2 y;
                y.x = __shfl_xor(v.x, bit, 64);
                y.y = __shfl_xor(v.y, bit, 64);
                float2 m0 = (i & bit) ? g[(l*8+q)*4+3] : g[(l*8+q)*4+0];
                float2 m1 = (i & bit) ? g[(l*8+q)*4+2] : g[(l*8+q)*4+1];
                v = cadd(cmul(m0, v), cmul(m1, y));
            }
        }
        vb[i] = v; __syncthreads();
        float2 a = vb[rho(i)];
        float sgn = (i & 128) ? -1.f : 1.f;
        size_t row = ((size_t)ch*256 + j) * 512;
        At[row + i]       = (_Float16)(sgn * a.x);
        At[row + 256 + i] = (_Float16)(sgn * a.y);
        Bt[row + i]       = (_Float16)a.x;
        Bt[row + 256 + i] = (_Float16)a.y;
    } else {
        // ---------------- extract -> fp16 in B-fragment order ---------------
        const int tb  = blockIdx.x - 2048;   // ptile 0..NPTILE-1
        const int tid = threadIdx.x;
        const int wv  = tid >> 6, lane = tid & 63;

        #pragma unroll
        for (int pp = 0; pp < 4; ++pp) {
            int pl = wv*4 + pp;
            int p  = tb*16 + pl;
            float2 v01 = make_float2(0.f,0.f), v23 = make_float2(0.f,0.f);
            if (p < NPATCH) {
                int b = p / (OH*OW); int r = p % (OH*OW);
                int oi = r / OW, oj = r % OW;
                int ci = lane >> 2, fi = lane & 3;
                const float* xb = x + (((size_t)(b*16 + ci))*64 + (oi*2 + fi))*64 + oj*2;
                v01 = *(const float2*)xb;
                v23 = *(const float2*)(xb + 2);
            }
            float ss = v01.x*v01.x + v01.y*v01.y + v23.x*v23.x + v23.y*v23.y;
            #pragma unroll
            for (int m = 1; m < 64; m <<= 1) ss += __shfl_xor(ss, m, 64);
            float inv = ss > 0.f ? 1.f / sqrtf(ss) : 0.f;
            f16x4 o;
            o[0] = (_Float16)(v01.x*inv); o[1] = (_Float16)(v01.y*inv);
            o[2] = (_Float16)(v23.x*inv); o[3] = (_Float16)(v23.y*inv);
            *(f16x4*)&sT[pl][lane*4] = o;
        }
        __syncthreads();

        #pragma unroll
        for (int e = 0; e < 2; ++e) {
            int vi = tid + e*256;            // 0..511
            int ks = vi >> 6, ln = vi & 63;
            int kq = ln >> 4, prow = ln & 15;
            f16x8 o = *(const f16x8*)&sT[prow][ks*32 + kq*8];
            ((f16x8*)sF)[(size_t)tb*512 + vi] = o;
        }
    }
}

// ---- 2. M' = upper-tri-doubled (A^T D A), K=512 fp16 MFMA, packed frag out -
__global__ __launch_bounds__(256) void build_Mp(const _Float16* __restrict__ At,
                                                const _Float16* __restrict__ Bt,
                                                _Float16* __restrict__ Mp) {
    const int ch = blockIdx.z;
    const int ti = blockIdx.y;                       // 0..15
    const int wv = threadIdx.x >> 6;
    const int jt = blockIdx.x * 4 + wv;              // 0..15
    const int jt0 = 2 * (ti >> 1);
    if (jt < jt0) return;
    const int lane = threadIdx.x & 63;
    const int c16 = lane & 15, kq = lane >> 4;
    const int h = ti >> 1;
    const int offt = 8*ti - (h*(h-1) + h*(ti & 1));
    const int pidx = offt + (jt >> 1) - h;
    _Float16* Mc = Mp + (size_t)ch * MPACK;

    f32x4 acc = {0.f, 0.f, 0.f, 0.f};
    if (jt >= ti) {
        const _Float16* Ar = At + ((size_t)ch*256 + ti*16 + c16) * 512 + kq*8;
        const _Float16* Br = Bt + ((size_t)ch*256 + jt*16 + c16) * 512 + kq*8;
        #pragma unroll
        for (int kk = 0; kk < 16; ++kk) {
            f16x8 af = *(const f16x8*)(Ar + kk*32);
            f16x8 bf = *(const f16x8*)(Br + kk*32);
            acc = __builtin_amdgcn_mfma_f32_16x16x32_f16(af, bf, acc, 0, 0, 0);
        }
    }
    int wsel = (jt & 1) * 16 + c16;
    int kqp = wsel >> 3, jj = wsel & 7;
    #pragma unroll
    for (int reg = 0; reg < 4; ++reg) {
        int i_g = ti*16 + kq*4 + reg;
        int j_g = jt*16 + c16;
        float val = (jt >= ti) ? acc[reg] : 0.f;
        val *= (j_g > i_g) ? 2.f : ((j_g == i_g) ? 1.f : 0.f);
        Mc[(size_t)((pidx*64 + kqp*16 + (kq*4 + reg)) * 8 + jj)] = (_Float16)val;
    }
}

// ---- 3. fused MFMA quadform: out[p,c] = s_p^T M'_c s_p + bias[c] -----------
// 512 blocks XCD-pinned; 8 waves x 64 patches; M' (72KB) in LDS via async DMA.
// Runtime t-loops keep live set under the 128-VGPR cap (r8/r9 forensics).
// This round: fdot2 packed fold (halves the binding VALU pipe) + setprio.
__global__ __attribute__((amdgpu_flat_work_group_size(512,512), amdgpu_waves_per_eu(2,2)))
void fusedqf(const _Float16* __restrict__ sF,
             const _Float16* __restrict__ Mp,
             const float* __restrict__ bias,
             float* __restrict__ out) {
    extern __shared__ _Float16 Mlds[];      // 36864 halves = 72 KB
    const int id   = blockIdx.x;
    const int xcd  = id & 7;
    const int g    = id >> 3;
    const int c    = g >> 3;
    const int tile = (g & 7) * 8 + xcd;
    const int tid  = threadIdx.x;
    const int lane = tid & 63;
    const int wv   = tid >> 6;
    const int prow = lane & 15, kq = lane >> 4;
    const int tp0  = tile*32 + wv*4;        // base ptile (of 16 patches)

    // async stage M' (9 x 1KB chunks per wave, zero VGPR cost)
    const _Float16* Msrc = Mp + (size_t)c * MPACK;
    #pragma unroll
    for (int it = 0; it < 9; ++it) {
        int off = (wv*9 + it) * 512;
        gload_lds16(Msrc + off + lane*8, Mlds + off);
    }

    // pass-A B fragments (ks 0..3), overlap with the LDS DMA
    f16x8 bfrag[4][4];
    #pragma unroll
    for (int pt = 0; pt < 4; ++pt) {
        const f16x8* src = (const f16x8*)sF + (size_t)(tp0 + pt)*512 + lane;
        #pragma unroll
        for (int ks = 0; ks < 4; ++ks)
            bfrag[pt][ks] = src[ks*64];
    }

    __syncthreads();   // drains DMA (vmcnt) + joins waves

    const _Float16* fold0 = sF + ((size_t)tp0*512 + (kq>>1)*16 + prow)*8 + (kq&1)*4;
    float o0 = 0.f, o1 = 0.f, o2 = 0.f, o3 = 0.f;
    int pidx = 0;

    f16x4 svn[4];
    #pragma unroll
    for (int pt = 0; pt < 4; ++pt)
        svn[pt] = *(const f16x4*)(fold0 + pt*4096);

    // ---- pass A: t = 0..7 (runtime), ks in [t>>1, 4) ----
    #pragma unroll 1
    for (int t = 0; t < 8; ++t) {
        const int h = t >> 1;
        f16x4 svc[4];
        #pragma unroll
        for (int pt = 0; pt < 4; ++pt) svc[pt] = svn[pt];
        #pragma unroll
        for (int pt = 0; pt < 4; ++pt)
            svn[pt] = *(const f16x4*)(fold0 + pt*4096 + (t+1)*256);

        f32x4 a0 = {0,0,0,0}, a1 = {0,0,0,0}, a2 = {0,0,0,0}, a3 = {0,0,0,0};
        __builtin_amdgcn_s_setprio(1);
        #pragma unroll
        for (int ks = 0; ks < 4; ++ks) {
            if (ks >= h) {                               // wave-uniform
                f16x8 m = *(const f16x8*)(Mlds + (size_t)pidx*512 + lane*8);
                a0 = __builtin_amdgcn_mfma_f32_16x16x32_f16(m, bfrag[0][ks], a0, 0, 0, 0);
                a1 = __builtin_amdgcn_mfma_f32_16x16x32_f16(m, bfrag[1][ks], a1, 0, 0, 0);
                a2 = __builtin_amdgcn_mfma_f32_16x16x32_f16(m, bfrag[2][ks], a2, 0, 0, 0);
                a3 = __builtin_amdgcn_mfma_f32_16x16x32_f16(m, bfrag[3][ks], a3, 0, 0, 0);
                ++pidx;
            }
        }
        __builtin_amdgcn_s_setprio(0);
        pidx += 4;   // skip this t's pass-B pairs (ks 4..7)

        o0 = fold4(svc[0], a0, o0);
        o1 = fold4(svc[1], a1, o1);
        o2 = fold4(svc[2], a2, o2);
        o3 = fold4(svc[3], a3, o3);
    }

    // ---- pass B: load ks 4..7 fragments, t = 0..15 (runtime) ----
    #pragma unroll
    for (int pt = 0; pt < 4; ++pt) {
        const f16x8* src = (const f16x8*)sF + (size_t)(tp0 + pt)*512 + lane;
        #pragma unroll
        for (int ks = 0; ks < 4; ++ks)
            bfrag[pt][ks] = src[(ks+4)*64];
    }

    pidx = 0;
    #pragma unroll
    for (int pt = 0; pt < 4; ++pt)
        svn[pt] = *(const f16x4*)(fold0 + pt*4096);

    #pragma unroll 1
    for (int t = 0; t < 16; ++t) {
        const int h = t >> 1;
        pidx += (h < 4) ? (4 - h) : 0;   // skip this t's pass-A pairs
        f16x4 svc[4];
        #pragma unroll
        for (int pt = 0; pt < 4; ++pt) svc[pt] = svn[pt];
        if (t < 15) {
            #pragma unroll
            for (int pt = 0; pt < 4; ++pt)
                svn[pt] = *(const f16x4*)(fold0 + pt*4096 + (t+1)*256);
        }

        f32x4 a0 = {0,0,0,0}, a1 = {0,0,0,0}, a2 = {0,0,0,0}, a3 = {0,0,0,0};
        __builtin_amdgcn_s_setprio(1);
        #pragma unroll
        for (int ks = 4; ks < 8; ++ks) {
            if (ks >= h) {                               // wave-uniform
                f16x8 m = *(const f16x8*)(Mlds + (size_t)pidx*512 + lane*8);
                a0 = __builtin_amdgcn_mfma_f32_16x16x32_f16(m, bfrag[0][ks-4], a0, 0, 0, 0);
                a1 = __builtin_amdgcn_mfma_f32_16x16x32_f16(m, bfrag[1][ks-4], a1, 0, 0, 0);
                a2 = __builtin_amdgcn_mfma_f32_16x16x32_f16(m, bfrag[2][ks-4], a2, 0, 0, 0);
                a3 = __builtin_amdgcn_mfma_f32_16x16x32_f16(m, bfrag[3][ks-4], a3, 0, 0, 0);
                ++pidx;
            }
        }
        __builtin_amdgcn_s_setprio(0);

        o0 = fold4(svc[0], a0, o0);
        o1 = fold4(svc[1], a1, o1);
        o2 = fold4(svc[2], a2, o2);
        o3 = fold4(svc[3], a3, o3);
    }

    float ov[4] = {o0, o1, o2, o3};
    float bc = bias[c];
    #pragma unroll
    for (int pt = 0; pt < 4; ++pt) {
        float v = ov[pt];
        v += __shfl_xor(v, 16, 64);
        v += __shfl_xor(v, 32, 64);
        if (kq == 0) {
            int p = (tp0 + pt)*16 + prow;
            if (p < NPATCH) {
                int b = p / (OH*OW); int r2 = p % (OH*OW);
                int oi = r2 / OW, oj = r2 % OW;
                out[(((size_t)(b*COUT + c))*OH + oi)*OW + oj] = v + bc;
            }
        }
    }
}

extern "C" void kernel_launch(void* const* d_in, const int* in_sizes, int n_in,
                              void* d_out, int out_size, void* d_ws, size_t ws_size,
                              hipStream_t stream) {
    const float* x    = (const float*)d_in[0];
    const float* w    = (const float*)d_in[1];
    const float* bias = (const float*)d_in[2];
    float* out = (float*)d_out;

    const size_t OFF_AT  = 0;                       // 8*256*512*2 = 2,097,152
    const size_t OFF_BT  = OFF_AT + 2097152;        // 2,097,152
    const size_t OFF_MP  = OFF_BT + 2097152;        // 8*36864*2 = 589,824
    const size_t OFF_SF  = OFF_MP + 589824;         // 2048*512*16 = 16,777,216
    const size_t TOTAL   = OFF_SF + 16777216;
    if (ws_size < TOTAL) return;

    char* ws = (char*)d_ws;
    _Float16* At = (_Float16*)(ws + OFF_AT);
    _Float16* Bt = (_Float16*)(ws + OFF_BT);
    _Float16* Mp = (_Float16*)(ws + OFF_MP);
    _Float16* sF = (_Float16*)(ws + OFF_SF);

    wext<<<2048 + NPTILE, 256, 0, stream>>>(w, At, Bt, x, sF);
    build_Mp<<<dim3(4, 16, COUT), 256, 0, stream>>>(At, Bt, Mp);
    fusedqf<<<NTILE*COUT, 512, MPACK*sizeof(_Float16), stream>>>(sF, Mp, bias, out);
}

// Round 12
// 54.193 us; speedup vs baseline: 4.0552x; 1.0819x over previous
//
#include <hip/hip_runtime.h>
#include <math.h>

#define NQ     8
#define DIM    256
#define LAYERS 3
#define COUT   8
#define NB     32
#define OH     31
#define OW     31
#define NPATCH (NB*OH*OW)     // 30752
#define PT_BLK 512
#define NTILE  64             // 64 tiles x 8 ch = 512 blocks, XCD-bijective
#define PTOT   (NTILE*PT_BLK) // 32768
#define NPTILE (PTOT/16)      // 2048 16-patch groups
#define NPAIR  72             // packed upper-tri (t,ks) pairs
#define MPACK  (NPAIR*64*8)   // 36864 halves per channel

typedef _Float16 f16x8 __attribute__((ext_vector_type(8)));
typedef _Float16 f16x4 __attribute__((ext_vector_type(4)));
typedef _Float16 f16x2 __attribute__((ext_vector_type(2)));
typedef __fp16   h16x2 __attribute__((ext_vector_type(2)));
typedef float    f32x4 __attribute__((ext_vector_type(4)));

__device__ __forceinline__ float2 cmul(float2 a, float2 b) {
    return make_float2(a.x*b.x - a.y*b.y, a.x*b.y + a.y*b.x);
}
__device__ __forceinline__ float2 cadd(float2 a, float2 b) {
    return make_float2(a.x + b.x, a.y + b.y);
}

// CNOT-ring permutation (verified round 1)
__device__ __forceinline__ int rho(int i) {
    #pragma unroll
    for (int q = 7; q >= 0; --q) {
        int t = (q + 1) & 7;
        if ((i >> (7 - q)) & 1) i ^= 1 << (7 - t);
    }
    return i;
}

// async global->LDS, 16B per lane, LDS dest = wave-uniform base + lane*16
__device__ __forceinline__ void gload_lds16(const _Float16* g, _Float16* l) {
    __builtin_amdgcn_global_load_lds(
        (const __attribute__((address_space(1))) void*)g,
        (__attribute__((address_space(3))) void*)l, 16, 0, 0);
}

// fold: o += dot(sv, a[0..3]) via packed f16 dot2 (halves the fold VALU).
__device__ __forceinline__ float fold4(f16x4 sv, f32x4 a, float o) {
    h16x2 s01 = __builtin_bit_cast(h16x2, (f16x2)__builtin_shufflevector(sv, sv, 0, 1));
    h16x2 s23 = __builtin_bit_cast(h16x2, (f16x2)__builtin_shufflevector(sv, sv, 2, 3));
    h16x2 y01 = __builtin_amdgcn_cvt_pkrtz(a[0], a[1]);
    h16x2 y23 = __builtin_amdgcn_cvt_pkrtz(a[2], a[3]);
    o = __builtin_amdgcn_fdot2(s01, y01, o, false);
    o = __builtin_amdgcn_fdot2(s23, y23, o, false);
    return o;
}

// ---- 1. merged dispatch: blocks [0,2048) build W columns, [2048,4096) extract
__global__ __launch_bounds__(256) void wext(const float* __restrict__ w,
                                            _Float16* __restrict__ At,
                                            _Float16* __restrict__ Bt,
                                            const float* __restrict__ x,
                                            _Float16* __restrict__ sF) {
    __shared__ float2 g[96];
    __shared__ float2 vb[256];
    __shared__ _Float16 sT[16][264];

    if (blockIdx.x < 2048) {
        // ---------------- build_W: col j of U = P K2 P K1 P K0 --------------
        const int j  = blockIdx.x & 255;
        const int ch = blockIdx.x >> 8;
        const int i  = threadIdx.x;
        if (i < 24) {
            const float* wp = w + (ch*24 + i)*3;
            float phi = wp[0], th = wp[1], om = wp[2];
            float cth = cosf(th * 0.5f), sth = sinf(th * 0.5f);
            float a = 0.5f * (phi + om), b = 0.5f * (phi - om);
            float sa, ca, sb, cb;
            sincosf(a, &sa, &ca);
            sincosf(b, &sb, &cb);
            g[i*4+0] = make_float2( cth*ca, -cth*sa);
            g[i*4+1] = make_float2(-sth*cb, -sth*sb);
            g[i*4+2] = make_float2( sth*cb, -sth*sb);
            g[i*4+3] = make_float2( cth*ca,  cth*sa);
        }
        __syncthreads();

        float2 v = make_float2(1.f, 0.f);
        #pragma unroll
        for (int q = 0; q < 8; ++q) {
            int iq = (i >> (7 - q)) & 1, jq = (j >> (7 - q)) & 1;
            v = cmul(v, g[q*4 + iq*2 + jq]);
        }

        #pragma unroll
        for (int l = 1; l < 3; ++l) {
            vb[i] = v; __syncthreads();
            v = vb[rho(i)]; __syncthreads();
            #pragma unroll
            for (int q = 0; q < 2; ++q) {
                int bit = 1 << (7 - q);
                vb[i] = v; __syncthreads();
                float2 y = vb[i ^ bit]; __syncthreads();
                float2 m0 = (i & bit) ? g[(l*8+q)*4+3] : g[(l*8+q)*4+0];
                float2 m1 = (i & bit) ? g[(l*8+q)*4+2] : g[(l*8+q)*4+1];
                v = cadd(cmul(m0, v), cmul(m1, y));
            }
            #pragma unroll
            for (int q = 2; q < 8; ++q) {
                int bit = 1 << (7 - q);
                float2 y;
                y.x = __shfl_xor(v.x, bit, 64);
                y.y = __shfl_xor(v.y, bit, 64);
                float2 m0 = (i & bit) ? g[(l*8+q)*4+3] : g[(l*8+q)*4+0];
                float2 m1 = (i & bit) ? g[(l*8+q)*4+2] : g[(l*8+q)*4+1];
                v = cadd(cmul(m0, v), cmul(m1, y));
            }
        }
        vb[i] = v; __syncthreads();
        float2 a = vb[rho(i)];
        float sgn = (i & 128) ? -1.f : 1.f;
        size_t row = ((size_t)ch*256 + j) * 512;
        At[row + i]       = (_Float16)(sgn * a.x);
        At[row + 256 + i] = (_Float16)(sgn * a.y);
        Bt[row + i]       = (_Float16)a.x;
        Bt[row + 256 + i] = (_Float16)a.y;
    } else {
        // ---------------- extract -> fp16 in B-fragment order ---------------
        const int tb  = blockIdx.x - 2048;   // ptile 0..NPTILE-1
        const int tid = threadIdx.x;
        const int wv  = tid >> 6, lane = tid & 63;

        #pragma unroll
        for (int pp = 0; pp < 4; ++pp) {
            int pl = wv*4 + pp;
            int p  = tb*16 + pl;
            float2 v01 = make_float2(0.f,0.f), v23 = make_float2(0.f,0.f);
            if (p < NPATCH) {
                int b = p / (OH*OW); int r = p % (OH*OW);
                int oi = r / OW, oj = r % OW;
                int ci = lane >> 2, fi = lane & 3;
                const float* xb = x + (((size_t)(b*16 + ci))*64 + (oi*2 + fi))*64 + oj*2;
                v01 = *(const float2*)xb;
                v23 = *(const float2*)(xb + 2);
            }
            float ss = v01.x*v01.x + v01.y*v01.y + v23.x*v23.x + v23.y*v23.y;
            #pragma unroll
            for (int m = 1; m < 64; m <<= 1) ss += __shfl_xor(ss, m, 64);
            float inv = ss > 0.f ? 1.f / sqrtf(ss) : 0.f;
            f16x4 o;
            o[0] = (_Float16)(v01.x*inv); o[1] = (_Float16)(v01.y*inv);
            o[2] = (_Float16)(v23.x*inv); o[3] = (_Float16)(v23.y*inv);
            *(f16x4*)&sT[pl][lane*4] = o;
        }
        __syncthreads();

        #pragma unroll
        for (int e = 0; e < 2; ++e) {
            int vi = tid + e*256;            // 0..511
            int ks = vi >> 6, ln = vi & 63;
            int kq = ln >> 4, prow = ln & 15;
            f16x8 o = *(const f16x8*)&sT[prow][ks*32 + kq*8];
            ((f16x8*)sF)[(size_t)tb*512 + vi] = o;
        }
    }
}

// ---- 2. M' = upper-tri-doubled (A^T D A), K=512 fp16 MFMA, packed frag out -
__global__ __launch_bounds__(256) void build_Mp(const _Float16* __restrict__ At,
                                                const _Float16* __restrict__ Bt,
                                                _Float16* __restrict__ Mp) {
    const int ch = blockIdx.z;
    const int ti = blockIdx.y;                       // 0..15
    const int wv = threadIdx.x >> 6;
    const int jt = blockIdx.x * 4 + wv;              // 0..15
    const int jt0 = 2 * (ti >> 1);
    if (jt < jt0) return;
    const int lane = threadIdx.x & 63;
    const int c16 = lane & 15, kq = lane >> 4;
    const int h = ti >> 1;
    const int offt = 8*ti - (h*(h-1) + h*(ti & 1));
    const int pidx = offt + (jt >> 1) - h;
    _Float16* Mc = Mp + (size_t)ch * MPACK;

    f32x4 acc = {0.f, 0.f, 0.f, 0.f};
    if (jt >= ti) {
        const _Float16* Ar = At + ((size_t)ch*256 + ti*16 + c16) * 512 + kq*8;
        const _Float16* Br = Bt + ((size_t)ch*256 + jt*16 + c16) * 512 + kq*8;
        #pragma unroll
        for (int kk = 0; kk < 16; ++kk) {
            f16x8 af = *(const f16x8*)(Ar + kk*32);
            f16x8 bf = *(const f16x8*)(Br + kk*32);
            acc = __builtin_amdgcn_mfma_f32_16x16x32_f16(af, bf, acc, 0, 0, 0);
        }
    }
    int wsel = (jt & 1) * 16 + c16;
    int kqp = wsel >> 3, jj = wsel & 7;
    #pragma unroll
    for (int reg = 0; reg < 4; ++reg) {
        int i_g = ti*16 + kq*4 + reg;
        int j_g = jt*16 + c16;
        float val = (jt >= ti) ? acc[reg] : 0.f;
        val *= (j_g > i_g) ? 2.f : ((j_g == i_g) ? 1.f : 0.f);
        Mc[(size_t)((pidx*64 + kqp*16 + (kq*4 + reg)) * 8 + jj)] = (_Float16)val;
    }
}

// ---- 3. fused MFMA quadform: out[p,c] = s_p^T M'_c s_p + bias[c] -----------
// 512 blocks XCD-pinned; 8 waves x 64 patches; M' (72KB) in LDS via async DMA.
// SINGLE DELTA vs r11: waves_per_eu (2,2) -> (2,4). max=2 was forbidding the
// second co-resident block per CU (8-wave block = 2 waves/SIMD already), which
// serialized the grid at 25% occupancy. (2,4) allows 2 blocks/CU: LDS 144/160
// KB, VGPR 16x128 = 2048 pool exactly. If allocator exceeds 128 VGPR we only
// fall back to today's 1 block/CU.
__global__ __attribute__((amdgpu_flat_work_group_size(512,512), amdgpu_waves_per_eu(2,4)))
void fusedqf(const _Float16* __restrict__ sF,
             const _Float16* __restrict__ Mp,
             const float* __restrict__ bias,
             float* __restrict__ out) {
    extern __shared__ _Float16 Mlds[];      // 36864 halves = 72 KB
    const int id   = blockIdx.x;
    const int xcd  = id & 7;
    const int g    = id >> 3;
    const int c    = g >> 3;
    const int tile = (g & 7) * 8 + xcd;
    const int tid  = threadIdx.x;
    const int lane = tid & 63;
    const int wv   = tid >> 6;
    const int prow = lane & 15, kq = lane >> 4;
    const int tp0  = tile*32 + wv*4;        // base ptile (of 16 patches)

    // async stage M' (9 x 1KB chunks per wave, zero VGPR cost)
    const _Float16* Msrc = Mp + (size_t)c * MPACK;
    #pragma unroll
    for (int it = 0; it < 9; ++it) {
        int off = (wv*9 + it) * 512;
        gload_lds16(Msrc + off + lane*8, Mlds + off);
    }

    // pass-A B fragments (ks 0..3), overlap with the LDS DMA
    f16x8 bfrag[4][4];
    #pragma unroll
    for (int pt = 0; pt < 4; ++pt) {
        const f16x8* src = (const f16x8*)sF + (size_t)(tp0 + pt)*512 + lane;
        #pragma unroll
        for (int ks = 0; ks < 4; ++ks)
            bfrag[pt][ks] = src[ks*64];
    }

    __syncthreads();   // drains DMA (vmcnt) + joins waves

    const _Float16* fold0 = sF + ((size_t)tp0*512 + (kq>>1)*16 + prow)*8 + (kq&1)*4;
    float o0 = 0.f, o1 = 0.f, o2 = 0.f, o3 = 0.f;
    int pidx = 0;

    f16x4 svn[4];
    #pragma unroll
    for (int pt = 0; pt < 4; ++pt)
        svn[pt] = *(const f16x4*)(fold0 + pt*4096);

    // ---- pass A: t = 0..7 (runtime), ks in [t>>1, 4) ----
    #pragma unroll 1
    for (int t = 0; t < 8; ++t) {
        const int h = t >> 1;
        f16x4 svc[4];
        #pragma unroll
        for (int pt = 0; pt < 4; ++pt) svc[pt] = svn[pt];
        #pragma unroll
        for (int pt = 0; pt < 4; ++pt)
            svn[pt] = *(const f16x4*)(fold0 + pt*4096 + (t+1)*256);

        f32x4 a0 = {0,0,0,0}, a1 = {0,0,0,0}, a2 = {0,0,0,0}, a3 = {0,0,0,0};
        __builtin_amdgcn_s_setprio(1);
        #pragma unroll
        for (int ks = 0; ks < 4; ++ks) {
            if (ks >= h) {                               // wave-uniform
                f16x8 m = *(const f16x8*)(Mlds + (size_t)pidx*512 + lane*8);
                a0 = __builtin_amdgcn_mfma_f32_16x16x32_f16(m, bfrag[0][ks], a0, 0, 0, 0);
                a1 = __builtin_amdgcn_mfma_f32_16x16x32_f16(m, bfrag[1][ks], a1, 0, 0, 0);
                a2 = __builtin_amdgcn_mfma_f32_16x16x32_f16(m, bfrag[2][ks], a2, 0, 0, 0);
                a3 = __builtin_amdgcn_mfma_f32_16x16x32_f16(m, bfrag[3][ks], a3, 0, 0, 0);
                ++pidx;
            }
        }
        __builtin_amdgcn_s_setprio(0);
        pidx += 4;   // skip this t's pass-B pairs (ks 4..7)

        o0 = fold4(svc[0], a0, o0);
        o1 = fold4(svc[1], a1, o1);
        o2 = fold4(svc[2], a2, o2);
        o3 = fold4(svc[3], a3, o3);
    }

    // ---- pass B: load ks 4..7 fragments, t = 0..15 (runtime) ----
    #pragma unroll
    for (int pt = 0; pt < 4; ++pt) {
        const f16x8* src = (const f16x8*)sF + (size_t)(tp0 + pt)*512 + lane;
        #pragma unroll
        for (int ks = 0; ks < 4; ++ks)
            bfrag[pt][ks] = src[(ks+4)*64];
    }

    pidx = 0;
    #pragma unroll
    for (int pt = 0; pt < 4; ++pt)
        svn[pt] = *(const f16x4*)(fold0 + pt*4096);

    #pragma unroll 1
    for (int t = 0; t < 16; ++t) {
        const int h = t >> 1;
        pidx += (h < 4) ? (4 - h) : 0;   // skip this t's pass-A pairs
        f16x4 svc[4];
        #pragma unroll
        for (int pt = 0; pt < 4; ++pt) svc[pt] = svn[pt];
        if (t < 15) {
            #pragma unroll
            for (int pt = 0; pt < 4; ++pt)
                svn[pt] = *(const f16x4*)(fold0 + pt*4096 + (t+1)*256);
        }

        f32x4 a0 = {0,0,0,0}, a1 = {0,0,0,0}, a2 = {0,0,0,0}, a3 = {0,0,0,0};
        __builtin_amdgcn_s_setprio(1);
        #pragma unroll
        for (int ks = 4; ks < 8; ++ks) {
            if (ks >= h) {                               // wave-uniform
                f16x8 m = *(const f16x8*)(Mlds + (size_t)pidx*512 + lane*8);
                a0 = __builtin_amdgcn_mfma_f32_16x16x32_f16(m, bfrag[0][ks-4], a0, 0, 0, 0);
                a1 = __builtin_amdgcn_mfma_f32_16x16x32_f16(m, bfrag[1][ks-4], a1, 0, 0, 0);
                a2 = __builtin_amdgcn_mfma_f32_16x16x32_f16(m, bfrag[2][ks-4], a2, 0, 0, 0);
                a3 = __builtin_amdgcn_mfma_f32_16x16x32_f16(m, bfrag[3][ks-4], a3, 0, 0, 0);
                ++pidx;
            }
        }
        __builtin_amdgcn_s_setprio(0);

        o0 = fold4(svc[0], a0, o0);
        o1 = fold4(svc[1], a1, o1);
        o2 = fold4(svc[2], a2, o2);
        o3 = fold4(svc[3], a3, o3);
    }

    float ov[4] = {o0, o1, o2, o3};
    float bc = bias[c];
    #pragma unroll
    for (int pt = 0; pt < 4; ++pt) {
        float v = ov[pt];
        v += __shfl_xor(v, 16, 64);
        v += __shfl_xor(v, 32, 64);
        if (kq == 0) {
            int p = (tp0 + pt)*16 + prow;
            if (p < NPATCH) {
                int b = p / (OH*OW); int r2 = p % (OH*OW);
                int oi = r2 / OW, oj = r2 % OW;
                out[(((size_t)(b*COUT + c))*OH + oi)*OW + oj] = v + bc;
            }
        }
    }
}

extern "C" void kernel_launch(void* const* d_in, const int* in_sizes, int n_in,
                              void* d_out, int out_size, void* d_ws, size_t ws_size,
                              hipStream_t stream) {
    const float* x    = (const float*)d_in[0];
    const float* w    = (const float*)d_in[1];
    const float* bias = (const float*)d_in[2];
    float* out = (float*)d_out;

    const size_t OFF_AT  = 0;                       // 8*256*512*2 = 2,097,152
    const size_t OFF_BT  = OFF_AT + 2097152;        // 2,097,152
    const size_t OFF_MP  = OFF_BT + 2097152;        // 8*36864*2 = 589,824
    const size_t OFF_SF  = OFF_MP + 589824;         // 2048*512*16 = 16,777,216
    const size_t TOTAL   = OFF_SF + 16777216;
    if (ws_size < TOTAL) return;

    char* ws = (char*)d_ws;
    _Float16* At = (_Float16*)(ws + OFF_AT);
    _Float16* Bt = (_Float16*)(ws + OFF_BT);
    _Float16* Mp = (_Float16*)(ws + OFF_MP);
    _Float16* sF = (_Float16*)(ws + OFF_SF);

    wext<<<2048 + NPTILE, 256, 0, stream>>>(w, At, Bt, x, sF);
    build_Mp<<<dim3(4, 16, COUT), 256, 0, stream>>>(At, Bt, Mp);
    fusedqf<<<NTILE*COUT, 512, MPACK*sizeof(_Float16), stream>>>(sF, Mp, bias, out);
}

// Round 13
// 54.092 us; speedup vs baseline: 4.0628x; 1.0019x over previous
//
#include <hip/hip_runtime.h>
#include <math.h>

#define NQ     8
#define DIM    256
#define LAYERS 3
#define COUT   8
#define NB     32
#define OH     31
#define OW     31
#define NPATCH (NB*OH*OW)     // 30752
#define PT_BLK 512
#define NTILE  64             // 64 tiles x 8 ch = 512 blocks, XCD-bijective
#define PTOT   (NTILE*PT_BLK) // 32768
#define NPTILE (PTOT/16)      // 2048 16-patch groups
#define NPAIR  72             // packed upper-tri (t,ks) pairs
#define MPACK  (NPAIR*64*8)   // 36864 halves per channel

typedef _Float16 f16x8 __attribute__((ext_vector_type(8)));
typedef _Float16 f16x4 __attribute__((ext_vector_type(4)));
typedef _Float16 f16x2 __attribute__((ext_vector_type(2)));
typedef __fp16   h16x2 __attribute__((ext_vector_type(2)));
typedef float    f32x4 __attribute__((ext_vector_type(4)));

__device__ __forceinline__ float2 cmul(float2 a, float2 b) {
    return make_float2(a.x*b.x - a.y*b.y, a.x*b.y + a.y*b.x);
}
__device__ __forceinline__ float2 cadd(float2 a, float2 b) {
    return make_float2(a.x + b.x, a.y + b.y);
}

// CNOT-ring permutation (verified round 1)
__device__ __forceinline__ int rho(int i) {
    #pragma unroll
    for (int q = 7; q >= 0; --q) {
        int t = (q + 1) & 7;
        if ((i >> (7 - q)) & 1) i ^= 1 << (7 - t);
    }
    return i;
}

// async global->LDS, 16B per lane, LDS dest = wave-uniform base + lane*16
__device__ __forceinline__ void gload_lds16(const _Float16* g, _Float16* l) {
    __builtin_amdgcn_global_load_lds(
        (const __attribute__((address_space(1))) void*)g,
        (__attribute__((address_space(3))) void*)l, 16, 0, 0);
}

// fold: o += dot(sv, a[0..3]) via packed f16 dot2
__device__ __forceinline__ float fold4(f16x4 sv, f32x4 a, float o) {
    h16x2 s01 = __builtin_bit_cast(h16x2, (f16x2)__builtin_shufflevector(sv, sv, 0, 1));
    h16x2 s23 = __builtin_bit_cast(h16x2, (f16x2)__builtin_shufflevector(sv, sv, 2, 3));
    h16x2 y01 = __builtin_amdgcn_cvt_pkrtz(a[0], a[1]);
    h16x2 y23 = __builtin_amdgcn_cvt_pkrtz(a[2], a[3]);
    o = __builtin_amdgcn_fdot2(s01, y01, o, false);
    o = __builtin_amdgcn_fdot2(s23, y23, o, false);
    return o;
}

// VALU-pipe row-of-16 reduce step: x += row_ror<n>(x). ctrl: 0x120|n.
__device__ __forceinline__ float dpp_ror_add(float x, int ctrl) {
    int xi = __builtin_bit_cast(int, x);
    int yi;
    switch (ctrl) {   // ctrl must be an immediate for the builtin
        case 0x128: yi = __builtin_amdgcn_update_dpp(0, xi, 0x128, 0xf, 0xf, true); break;
        case 0x124: yi = __builtin_amdgcn_update_dpp(0, xi, 0x124, 0xf, 0xf, true); break;
        case 0x122: yi = __builtin_amdgcn_update_dpp(0, xi, 0x122, 0xf, 0xf, true); break;
        default:    yi = __builtin_amdgcn_update_dpp(0, xi, 0x121, 0xf, 0xf, true); break;
    }
    return x + __builtin_bit_cast(float, yi);
}

// ---- 1. merged dispatch: blocks [0,2048) build W columns, [2048,4096) extract
__global__ __launch_bounds__(256) void wext(const float* __restrict__ w,
                                            _Float16* __restrict__ At,
                                            _Float16* __restrict__ Bt,
                                            const float* __restrict__ x,
                                            _Float16* __restrict__ sF) {
    __shared__ float2 g[96];
    __shared__ float2 vb[256];
    __shared__ _Float16 sT[16][264];
    __shared__ float rsums[16][4];

    if (blockIdx.x < 2048) {
        // ---------------- build_W: col j of U = P K2 P K1 P K0 --------------
        const int j  = blockIdx.x & 255;
        const int ch = blockIdx.x >> 8;
        const int i  = threadIdx.x;
        if (i < 24) {
            const float* wp = w + (ch*24 + i)*3;
            float phi = wp[0], th = wp[1], om = wp[2];
            float cth = cosf(th * 0.5f), sth = sinf(th * 0.5f);
            float a = 0.5f * (phi + om), b = 0.5f * (phi - om);
            float sa, ca, sb, cb;
            sincosf(a, &sa, &ca);
            sincosf(b, &sb, &cb);
            g[i*4+0] = make_float2( cth*ca, -cth*sa);
            g[i*4+1] = make_float2(-sth*cb, -sth*sb);
            g[i*4+2] = make_float2( sth*cb, -sth*sb);
            g[i*4+3] = make_float2( cth*ca,  cth*sa);
        }
        __syncthreads();

        float2 v = make_float2(1.f, 0.f);
        #pragma unroll
        for (int q = 0; q < 8; ++q) {
            int iq = (i >> (7 - q)) & 1, jq = (j >> (7 - q)) & 1;
            v = cmul(v, g[q*4 + iq*2 + jq]);
        }

        #pragma unroll
        for (int l = 1; l < 3; ++l) {
            vb[i] = v; __syncthreads();
            v = vb[rho(i)]; __syncthreads();
            #pragma unroll
            for (int q = 0; q < 2; ++q) {
                int bit = 1 << (7 - q);
                vb[i] = v; __syncthreads();
                float2 y = vb[i ^ bit]; __syncthreads();
                float2 m0 = (i & bit) ? g[(l*8+q)*4+3] : g[(l*8+q)*4+0];
                float2 m1 = (i & bit) ? g[(l*8+q)*4+2] : g[(l*8+q)*4+1];
                v = cadd(cmul(m0, v), cmul(m1, y));
            }
            #pragma unroll
            for (int q = 2; q < 8; ++q) {
                int bit = 1 << (7 - q);
                float2 y;
                y.x = __shfl_xor(v.x, bit, 64);
                y.y = __shfl_xor(v.y, bit, 64);
                float2 m0 = (i & bit) ? g[(l*8+q)*4+3] : g[(l*8+q)*4+0];
                float2 m1 = (i & bit) ? g[(l*8+q)*4+2] : g[(l*8+q)*4+1];
                v = cadd(cmul(m0, v), cmul(m1, y));
            }
        }
        vb[i] = v; __syncthreads();
        float2 a = vb[rho(i)];
        float sgn = (i & 128) ? -1.f : 1.f;
        size_t row = ((size_t)ch*256 + j) * 512;
        At[row + i]       = (_Float16)(sgn * a.x);
        At[row + 256 + i] = (_Float16)(sgn * a.y);
        Bt[row + i]       = (_Float16)a.x;
        Bt[row + 256 + i] = (_Float16)a.y;
    } else {
        // ------- extract -> fp16 B-fragment order; DPP row-reduce norms -----
        const int tb  = blockIdx.x - 2048;   // ptile 0..NPTILE-1
        const int tid = threadIdx.x;
        const int wv  = tid >> 6, lane = tid & 63;

        float2 va[4], vc[4];                 // per-pp loaded values (16 VGPR)
        #pragma unroll
        for (int pp = 0; pp < 4; ++pp) {
            int pl = wv*4 + pp;
            int p  = tb*16 + pl;
            float2 v01 = make_float2(0.f,0.f), v23 = make_float2(0.f,0.f);
            if (p < NPATCH) {
                int b = p / (OH*OW); int r = p % (OH*OW);
                int oi = r / OW, oj = r % OW;
                int ci = lane >> 2, fi = lane & 3;
                const float* xb = x + (((size_t)(b*16 + ci))*64 + (oi*2 + fi))*64 + oj*2;
                v01 = *(const float2*)xb;
                v23 = *(const float2*)(xb + 2);
            }
            va[pp] = v01; vc[pp] = v23;
            float ss = v01.x*v01.x + v01.y*v01.y + v23.x*v23.x + v23.y*v23.y;
            // row-of-16 sum on the VALU pipe (replaces 6-step 64-lane shfl butterfly)
            ss = dpp_ror_add(ss, 0x128);
            ss = dpp_ror_add(ss, 0x124);
            ss = dpp_ror_add(ss, 0x122);
            ss = dpp_ror_add(ss, 0x121);
            if ((lane & 15) == 0) rsums[pl][lane >> 4] = ss;
        }
        __syncthreads();

        #pragma unroll
        for (int pp = 0; pp < 4; ++pp) {
            int pl = wv*4 + pp;
            float tot = rsums[pl][0] + rsums[pl][1] + rsums[pl][2] + rsums[pl][3];
            float inv = tot > 0.f ? 1.f / sqrtf(tot) : 0.f;
            f16x4 o;
            o[0] = (_Float16)(va[pp].x*inv); o[1] = (_Float16)(va[pp].y*inv);
            o[2] = (_Float16)(vc[pp].x*inv); o[3] = (_Float16)(vc[pp].y*inv);
            *(f16x4*)&sT[pl][lane*4] = o;
        }
        __syncthreads();

        #pragma unroll
        for (int e = 0; e < 2; ++e) {
            int vi = tid + e*256;            // 0..511
            int ks = vi >> 6, ln = vi & 63;
            int kq = ln >> 4, prow = ln & 15;
            f16x8 o = *(const f16x8*)&sT[prow][ks*32 + kq*8];
            ((f16x8*)sF)[(size_t)tb*512 + vi] = o;
        }
    }
}

// ---- 2. M' = upper-tri-doubled (A^T D A), K=512 fp16 MFMA, packed frag out -
__global__ __launch_bounds__(256) void build_Mp(const _Float16* __restrict__ At,
                                                const _Float16* __restrict__ Bt,
                                                _Float16* __restrict__ Mp) {
    const int ch = blockIdx.z;
    const int ti = blockIdx.y;                       // 0..15
    const int wv = threadIdx.x >> 6;
    const int jt = blockIdx.x * 4 + wv;              // 0..15
    const int jt0 = 2 * (ti >> 1);
    if (jt < jt0) return;
    const int lane = threadIdx.x & 63;
    const int c16 = lane & 15, kq = lane >> 4;
    const int h = ti >> 1;
    const int offt = 8*ti - (h*(h-1) + h*(ti & 1));
    const int pidx = offt + (jt >> 1) - h;
    _Float16* Mc = Mp + (size_t)ch * MPACK;

    f32x4 acc = {0.f, 0.f, 0.f, 0.f};
    if (jt >= ti) {
        const _Float16* Ar = At + ((size_t)ch*256 + ti*16 + c16) * 512 + kq*8;
        const _Float16* Br = Bt + ((size_t)ch*256 + jt*16 + c16) * 512 + kq*8;
        #pragma unroll
        for (int kk = 0; kk < 16; ++kk) {
            f16x8 af = *(const f16x8*)(Ar + kk*32);
            f16x8 bf = *(const f16x8*)(Br + kk*32);
            acc = __builtin_amdgcn_mfma_f32_16x16x32_f16(af, bf, acc, 0, 0, 0);
        }
    }
    int wsel = (jt & 1) * 16 + c16;
    int kqp = wsel >> 3, jj = wsel & 7;
    #pragma unroll
    for (int reg = 0; reg < 4; ++reg) {
        int i_g = ti*16 + kq*4 + reg;
        int j_g = jt*16 + c16;
        float val = (jt >= ti) ? acc[reg] : 0.f;
        val *= (j_g > i_g) ? 2.f : ((j_g == i_g) ? 1.f : 0.f);
        Mc[(size_t)((pidx*64 + kqp*16 + (kq*4 + reg)) * 8 + jj)] = (_Float16)val;
    }
}

// ---- 3. fused MFMA quadform: out[p,c] = s_p^T M'_c s_p + bias[c] -----------
// BYTE-IDENTICAL to r12 (attribution: this round changes only extract).
__global__ __attribute__((amdgpu_flat_work_group_size(512,512), amdgpu_waves_per_eu(2,4)))
void fusedqf(const _Float16* __restrict__ sF,
             const _Float16* __restrict__ Mp,
             const float* __restrict__ bias,
             float* __restrict__ out) {
    extern __shared__ _Float16 Mlds[];      // 36864 halves = 72 KB
    const int id   = blockIdx.x;
    const int xcd  = id & 7;
    const int g    = id >> 3;
    const int c    = g >> 3;
    const int tile = (g & 7) * 8 + xcd;
    const int tid  = threadIdx.x;
    const int lane = tid & 63;
    const int wv   = tid >> 6;
    const int prow = lane & 15, kq = lane >> 4;
    const int tp0  = tile*32 + wv*4;        // base ptile (of 16 patches)

    // async stage M' (9 x 1KB chunks per wave, zero VGPR cost)
    const _Float16* Msrc = Mp + (size_t)c * MPACK;
    #pragma unroll
    for (int it = 0; it < 9; ++it) {
        int off = (wv*9 + it) * 512;
        gload_lds16(Msrc + off + lane*8, Mlds + off);
    }

    // pass-A B fragments (ks 0..3), overlap with the LDS DMA
    f16x8 bfrag[4][4];
    #pragma unroll
    for (int pt = 0; pt < 4; ++pt) {
        const f16x8* src = (const f16x8*)sF + (size_t)(tp0 + pt)*512 + lane;
        #pragma unroll
        for (int ks = 0; ks < 4; ++ks)
            bfrag[pt][ks] = src[ks*64];
    }

    __syncthreads();   // drains DMA (vmcnt) + joins waves

    const _Float16* fold0 = sF + ((size_t)tp0*512 + (kq>>1)*16 + prow)*8 + (kq&1)*4;
    float o0 = 0.f, o1 = 0.f, o2 = 0.f, o3 = 0.f;
    int pidx = 0;

    f16x4 svn[4];
    #pragma unroll
    for (int pt = 0; pt < 4; ++pt)
        svn[pt] = *(const f16x4*)(fold0 + pt*4096);

    // ---- pass A: t = 0..7 (runtime), ks in [t>>1, 4) ----
    #pragma unroll 1
    for (int t = 0; t < 8; ++t) {
        const int h = t >> 1;
        f16x4 svc[4];
        #pragma unroll
        for (int pt = 0; pt < 4; ++pt) svc[pt] = svn[pt];
        #pragma unroll
        for (int pt = 0; pt < 4; ++pt)
            svn[pt] = *(const f16x4*)(fold0 + pt*4096 + (t+1)*256);

        f32x4 a0 = {0,0,0,0}, a1 = {0,0,0,0}, a2 = {0,0,0,0}, a3 = {0,0,0,0};
        __builtin_amdgcn_s_setprio(1);
        #pragma unroll
        for (int ks = 0; ks < 4; ++ks) {
            if (ks >= h) {                               // wave-uniform
                f16x8 m = *(const f16x8*)(Mlds + (size_t)pidx*512 + lane*8);
                a0 = __builtin_amdgcn_mfma_f32_16x16x32_f16(m, bfrag[0][ks], a0, 0, 0, 0);
                a1 = __builtin_amdgcn_mfma_f32_16x16x32_f16(m, bfrag[1][ks], a1, 0, 0, 0);
                a2 = __builtin_amdgcn_mfma_f32_16x16x32_f16(m, bfrag[2][ks], a2, 0, 0, 0);
                a3 = __builtin_amdgcn_mfma_f32_16x16x32_f16(m, bfrag[3][ks], a3, 0, 0, 0);
                ++pidx;
            }
        }
        __builtin_amdgcn_s_setprio(0);
        pidx += 4;   // skip this t's pass-B pairs (ks 4..7)

        o0 = fold4(svc[0], a0, o0);
        o1 = fold4(svc[1], a1, o1);
        o2 = fold4(svc[2], a2, o2);
        o3 = fold4(svc[3], a3, o3);
    }

    // ---- pass B: load ks 4..7 fragments, t = 0..15 (runtime) ----
    #pragma unroll
    for (int pt = 0; pt < 4; ++pt) {
        const f16x8* src = (const f16x8*)sF + (size_t)(tp0 + pt)*512 + lane;
        #pragma unroll
        for (int ks = 0; ks < 4; ++ks)
            bfrag[pt][ks] = src[(ks+4)*64];
    }

    pidx = 0;
    #pragma unroll
    for (int pt = 0; pt < 4; ++pt)
        svn[pt] = *(const f16x4*)(fold0 + pt*4096);

    #pragma unroll 1
    for (int t = 0; t < 16; ++t) {
        const int h = t >> 1;
        pidx += (h < 4) ? (4 - h) : 0;   // skip this t's pass-A pairs
        f16x4 svc[4];
        #pragma unroll
        for (int pt = 0; pt < 4; ++pt) svc[pt] = svn[pt];
        if (t < 15) {
            #pragma unroll
            for (int pt = 0; pt < 4; ++pt)
                svn[pt] = *(const f16x4*)(fold0 + pt*4096 + (t+1)*256);
        }

        f32x4 a0 = {0,0,0,0}, a1 = {0,0,0,0}, a2 = {0,0,0,0}, a3 = {0,0,0,0};
        __builtin_amdgcn_s_setprio(1);
        #pragma unroll
        for (int ks = 4; ks < 8; ++ks) {
            if (ks >= h) {                               // wave-uniform
                f16x8 m = *(const f16x8*)(Mlds + (size_t)pidx*512 + lane*8);
                a0 = __builtin_amdgcn_mfma_f32_16x16x32_f16(m, bfrag[0][ks-4], a0, 0, 0, 0);
                a1 = __builtin_amdgcn_mfma_f32_16x16x32_f16(m, bfrag[1][ks-4], a1, 0, 0, 0);
                a2 = __builtin_amdgcn_mfma_f32_16x16x32_f16(m, bfrag[2][ks-4], a2, 0, 0, 0);
                a3 = __builtin_amdgcn_mfma_f32_16x16x32_f16(m, bfrag[3][ks-4], a3, 0, 0, 0);
                ++pidx;
            }
        }
        __builtin_amdgcn_s_setprio(0);

        o0 = fold4(svc[0], a0, o0);
        o1 = fold4(svc[1], a1, o1);
        o2 = fold4(svc[2], a2, o2);
        o3 = fold4(svc[3], a3, o3);
    }

    float ov[4] = {o0, o1, o2, o3};
    float bc = bias[c];
    #pragma unroll
    for (int pt = 0; pt < 4; ++pt) {
        float v = ov[pt];
        v += __shfl_xor(v, 16, 64);
        v += __shfl_xor(v, 32, 64);
        if (kq == 0) {
            int p = (tp0 + pt)*16 + prow;
            if (p < NPATCH) {
                int b = p / (OH*OW); int r2 = p % (OH*OW);
                int oi = r2 / OW, oj = r2 % OW;
                out[(((size_t)(b*COUT + c))*OH + oi)*OW + oj] = v + bc;
            }
        }
    }
}

extern "C" void kernel_launch(void* const* d_in, const int* in_sizes, int n_in,
                              void* d_out, int out_size, void* d_ws, size_t ws_size,
                              hipStream_t stream) {
    const float* x    = (const float*)d_in[0];
    const float* w    = (const float*)d_in[1];
    const float* bias = (const float*)d_in[2];
    float* out = (float*)d_out;

    const size_t OFF_AT  = 0;                       // 8*256*512*2 = 2,097,152
    const size_t OFF_BT  = OFF_AT + 2097152;        // 2,097,152
    const size_t OFF_MP  = OFF_BT + 2097152;        // 8*36864*2 = 589,824
    const size_t OFF_SF  = OFF_MP + 589824;         // 2048*512*16 = 16,777,216
    const size_t TOTAL   = OFF_SF + 16777216;
    if (ws_size < TOTAL) return;

    char* ws = (char*)d_ws;
    _Float16* At = (_Float16*)(ws + OFF_AT);
    _Float16* Bt = (_Float16*)(ws + OFF_BT);
    _Float16* Mp = (_Float16*)(ws + OFF_MP);
    _Float16* sF = (_Float16*)(ws + OFF_SF);

    wext<<<2048 + NPTILE, 256, 0, stream>>>(w, At, Bt, x, sF);
    build_Mp<<<dim3(4, 16, COUT), 256, 0, stream>>>(At, Bt, Mp);
    fusedqf<<<NTILE*COUT, 512, MPACK*sizeof(_Float16), stream>>>(sF, Mp, bias, out);
}

// Round 14
// 52.353 us; speedup vs baseline: 4.1977x; 1.0332x over previous
//
#include <hip/hip_runtime.h>
#include <math.h>

#define NQ     8
#define DIM    256
#define LAYERS 3
#define COUT   8
#define NB     32
#define OH     31
#define OW     31
#define NPATCH (NB*OH*OW)     // 30752
#define PT_BLK 512
#define NTILE  64             // 64 tiles x 8 ch = 512 blocks, XCD-bijective
#define PTOT   (NTILE*PT_BLK) // 32768
#define NPTILE (PTOT/16)      // 2048 16-patch groups
#define NPAIR  72             // packed upper-tri (t,ks) pairs
#define MPACK  (NPAIR*64*8)   // 36864 halves per channel
#define NWBLK  512            // W-part blocks (4 columns each, 1 wave/column)

typedef _Float16 f16x8 __attribute__((ext_vector_type(8)));
typedef _Float16 f16x4 __attribute__((ext_vector_type(4)));
typedef _Float16 f16x2 __attribute__((ext_vector_type(2)));
typedef __fp16   h16x2 __attribute__((ext_vector_type(2)));
typedef float    f32x4 __attribute__((ext_vector_type(4)));

__device__ __forceinline__ float2 cmul(float2 a, float2 b) {
    return make_float2(a.x*b.x - a.y*b.y, a.x*b.y + a.y*b.x);
}
__device__ __forceinline__ float2 cadd(float2 a, float2 b) {
    return make_float2(a.x + b.x, a.y + b.y);
}

// CNOT-ring permutation (verified round 1)
__device__ __forceinline__ int rho(int i) {
    #pragma unroll
    for (int q = 7; q >= 0; --q) {
        int t = (q + 1) & 7;
        if ((i >> (7 - q)) & 1) i ^= 1 << (7 - t);
    }
    return i;
}

// async global->LDS, 16B per lane, LDS dest = wave-uniform base + lane*16
__device__ __forceinline__ void gload_lds16(const _Float16* g, _Float16* l) {
    __builtin_amdgcn_global_load_lds(
        (const __attribute__((address_space(1))) void*)g,
        (__attribute__((address_space(3))) void*)l, 16, 0, 0);
}

// fold: o += dot(sv, a[0..3]) via packed f16 dot2
__device__ __forceinline__ float fold4(f16x4 sv, f32x4 a, float o) {
    h16x2 s01 = __builtin_bit_cast(h16x2, (f16x2)__builtin_shufflevector(sv, sv, 0, 1));
    h16x2 s23 = __builtin_bit_cast(h16x2, (f16x2)__builtin_shufflevector(sv, sv, 2, 3));
    h16x2 y01 = __builtin_amdgcn_cvt_pkrtz(a[0], a[1]);
    h16x2 y23 = __builtin_amdgcn_cvt_pkrtz(a[2], a[3]);
    o = __builtin_amdgcn_fdot2(s01, y01, o, false);
    o = __builtin_amdgcn_fdot2(s23, y23, o, false);
    return o;
}

// VALU-pipe row-of-16 reduce step: x += row_ror<n>(x). ctrl: 0x120|n.
__device__ __forceinline__ float dpp_ror_add(float x, int ctrl) {
    int xi = __builtin_bit_cast(int, x);
    int yi;
    switch (ctrl) {
        case 0x128: yi = __builtin_amdgcn_update_dpp(0, xi, 0x128, 0xf, 0xf, true); break;
        case 0x124: yi = __builtin_amdgcn_update_dpp(0, xi, 0x124, 0xf, 0xf, true); break;
        case 0x122: yi = __builtin_amdgcn_update_dpp(0, xi, 0x122, 0xf, 0xf, true); break;
        default:    yi = __builtin_amdgcn_update_dpp(0, xi, 0x121, 0xf, 0xf, true); break;
    }
    return x + __builtin_bit_cast(float, yi);
}

// ---- 1. merged dispatch: blocks [0,512) build W (wave/column, 4-row pack),
//         blocks [512, 512+2048) extract
__global__ __launch_bounds__(256) void wext(const float* __restrict__ w,
                                            _Float16* __restrict__ At,
                                            _Float16* __restrict__ Bt,
                                            const float* __restrict__ x,
                                            _Float16* __restrict__ sF) {
    __shared__ float2 g[96];
    __shared__ float2 vb[1024];          // 4 waves x 256 rows
    __shared__ _Float16 sT[16][264];
    __shared__ float rsums[16][4];

    if (blockIdx.x < NWBLK) {
        // -------- build_W: wave wv handles column col; lane holds 4 rows ----
        const int ch  = blockIdx.x >> 6;
        const int wv  = threadIdx.x >> 6;
        const int l   = threadIdx.x & 63;
        const int col = (blockIdx.x & 63) * 4 + wv;

        if (threadIdx.x < 24) {
            const float* wp = w + (ch*24 + threadIdx.x)*3;
            float phi = wp[0], th = wp[1], om = wp[2];
            float cth = cosf(th * 0.5f), sth = sinf(th * 0.5f);
            float a = 0.5f * (phi + om), b = 0.5f * (phi - om);
            float sa, ca, sb, cb;
            sincosf(a, &sa, &ca);
            sincosf(b, &sb, &cb);
            g[threadIdx.x*4+0] = make_float2( cth*ca, -cth*sa);
            g[threadIdx.x*4+1] = make_float2(-sth*cb, -sth*sb);
            g[threadIdx.x*4+2] = make_float2( sth*cb, -sth*sb);
            g[threadIdx.x*4+3] = make_float2( cth*ca,  cth*sa);
        }
        __syncthreads();                 // the ONLY barrier in the W path

        float2* vcol = vb + wv * 256;
        float2 v[4];
        #pragma unroll
        for (int k = 0; k < 4; ++k) {
            int r = l + 64*k;
            float2 acc = make_float2(1.f, 0.f);
            #pragma unroll
            for (int q = 0; q < 8; ++q) {
                int iq = (r >> (7 - q)) & 1, jq = (col >> (7 - q)) & 1;
                acc = cmul(acc, g[q*4 + iq*2 + jq]);
            }
            v[k] = acc;
        }

        #pragma unroll
        for (int lay = 1; lay < 3; ++lay) {
            // rho perm (intra-wave LDS, no barrier: disjoint 256-slot region)
            #pragma unroll
            for (int k = 0; k < 4; ++k) vcol[l + 64*k] = v[k];
            #pragma unroll
            for (int k = 0; k < 4; ++k) v[k] = vcol[rho(l + 64*k)];

            // q=0 (bit7): partner row = k^2 (in-register)
            {
                const float2 g0 = g[(lay*8+0)*4+0], g1 = g[(lay*8+0)*4+1];
                const float2 g2 = g[(lay*8+0)*4+2], g3 = g[(lay*8+0)*4+3];
                float2 nv[4];
                #pragma unroll
                for (int k = 0; k < 4; ++k) {
                    float2 xx = v[k], yy = v[k^2];
                    nv[k] = (k & 2) ? cadd(cmul(g2, yy), cmul(g3, xx))
                                    : cadd(cmul(g0, xx), cmul(g1, yy));
                }
                #pragma unroll
                for (int k = 0; k < 4; ++k) v[k] = nv[k];
            }
            // q=1 (bit6): partner row = k^1 (in-register)
            {
                const float2 g0 = g[(lay*8+1)*4+0], g1 = g[(lay*8+1)*4+1];
                const float2 g2 = g[(lay*8+1)*4+2], g3 = g[(lay*8+1)*4+3];
                float2 nv[4];
                #pragma unroll
                for (int k = 0; k < 4; ++k) {
                    float2 xx = v[k], yy = v[k^1];
                    nv[k] = (k & 1) ? cadd(cmul(g2, yy), cmul(g3, xx))
                                    : cadd(cmul(g0, xx), cmul(g1, yy));
                }
                #pragma unroll
                for (int k = 0; k < 4; ++k) v[k] = nv[k];
            }
            // q=2..7: lane-bit partners via shfl_xor
            #pragma unroll
            for (int q = 2; q < 8; ++q) {
                int bit = 1 << (7 - q);
                const float2 g0 = g[(lay*8+q)*4+0], g1 = g[(lay*8+q)*4+1];
                const float2 g2 = g[(lay*8+q)*4+2], g3 = g[(lay*8+q)*4+3];
                #pragma unroll
                for (int k = 0; k < 4; ++k) {
                    float2 yy;
                    yy.x = __shfl_xor(v[k].x, bit, 64);
                    yy.y = __shfl_xor(v[k].y, bit, 64);
                    float2 m0 = (l & bit) ? g3 : g0;
                    float2 m1 = (l & bit) ? g2 : g1;
                    v[k] = cadd(cmul(m0, v[k]), cmul(m1, yy));
                }
            }
        }
        // final rho perm
        #pragma unroll
        for (int k = 0; k < 4; ++k) vcol[l + 64*k] = v[k];
        #pragma unroll
        for (int k = 0; k < 4; ++k) v[k] = vcol[rho(l + 64*k)];

        size_t rowb = ((size_t)ch*256 + col) * 512;
        #pragma unroll
        for (int k = 0; k < 4; ++k) {
            int r = l + 64*k;
            float sgn = (r & 128) ? -1.f : 1.f;
            At[rowb + r]       = (_Float16)(sgn * v[k].x);
            At[rowb + 256 + r] = (_Float16)(sgn * v[k].y);
            Bt[rowb + r]       = (_Float16)v[k].x;
            Bt[rowb + 256 + r] = (_Float16)v[k].y;
        }
    } else {
        // ------- extract -> fp16 B-fragment order; DPP row-reduce norms -----
        const int tb  = blockIdx.x - NWBLK;  // ptile 0..NPTILE-1
        const int tid = threadIdx.x;
        const int wv  = tid >> 6, lane = tid & 63;

        float2 va[4], vc[4];
        #pragma unroll
        for (int pp = 0; pp < 4; ++pp) {
            int pl = wv*4 + pp;
            int p  = tb*16 + pl;
            float2 v01 = make_float2(0.f,0.f), v23 = make_float2(0.f,0.f);
            if (p < NPATCH) {
                int b = p / (OH*OW); int r = p % (OH*OW);
                int oi = r / OW, oj = r % OW;
                int ci = lane >> 2, fi = lane & 3;
                const float* xb = x + (((size_t)(b*16 + ci))*64 + (oi*2 + fi))*64 + oj*2;
                v01 = *(const float2*)xb;
                v23 = *(const float2*)(xb + 2);
            }
            va[pp] = v01; vc[pp] = v23;
            float ss = v01.x*v01.x + v01.y*v01.y + v23.x*v23.x + v23.y*v23.y;
            ss = dpp_ror_add(ss, 0x128);
            ss = dpp_ror_add(ss, 0x124);
            ss = dpp_ror_add(ss, 0x122);
            ss = dpp_ror_add(ss, 0x121);
            if ((lane & 15) == 0) rsums[pl][lane >> 4] = ss;
        }
        __syncthreads();

        #pragma unroll
        for (int pp = 0; pp < 4; ++pp) {
            int pl = wv*4 + pp;
            float tot = rsums[pl][0] + rsums[pl][1] + rsums[pl][2] + rsums[pl][3];
            float inv = tot > 0.f ? 1.f / sqrtf(tot) : 0.f;
            f16x4 o;
            o[0] = (_Float16)(va[pp].x*inv); o[1] = (_Float16)(va[pp].y*inv);
            o[2] = (_Float16)(vc[pp].x*inv); o[3] = (_Float16)(vc[pp].y*inv);
            *(f16x4*)&sT[pl][lane*4] = o;
        }
        __syncthreads();

        #pragma unroll
        for (int e = 0; e < 2; ++e) {
            int vi = tid + e*256;            // 0..511
            int ks = vi >> 6, ln = vi & 63;
            int kq = ln >> 4, prow = ln & 15;
            f16x8 o = *(const f16x8*)&sT[prow][ks*32 + kq*8];
            ((f16x8*)sF)[(size_t)tb*512 + vi] = o;
        }
    }
}

// ---- 2. M' = upper-tri-doubled (A^T D A), K=512 fp16 MFMA, packed frag out -
__global__ __launch_bounds__(256) void build_Mp(const _Float16* __restrict__ At,
                                                const _Float16* __restrict__ Bt,
                                                _Float16* __restrict__ Mp) {
    const int ch = blockIdx.z;
    const int ti = blockIdx.y;                       // 0..15
    const int wv = threadIdx.x >> 6;
    const int jt = blockIdx.x * 4 + wv;              // 0..15
    const int jt0 = 2 * (ti >> 1);
    if (jt < jt0) return;
    const int lane = threadIdx.x & 63;
    const int c16 = lane & 15, kq = lane >> 4;
    const int h = ti >> 1;
    const int offt = 8*ti - (h*(h-1) + h*(ti & 1));
    const int pidx = offt + (jt >> 1) - h;
    _Float16* Mc = Mp + (size_t)ch * MPACK;

    f32x4 acc = {0.f, 0.f, 0.f, 0.f};
    if (jt >= ti) {
        const _Float16* Ar = At + ((size_t)ch*256 + ti*16 + c16) * 512 + kq*8;
        const _Float16* Br = Bt + ((size_t)ch*256 + jt*16 + c16) * 512 + kq*8;
        #pragma unroll
        for (int kk = 0; kk < 16; ++kk) {
            f16x8 af = *(const f16x8*)(Ar + kk*32);
            f16x8 bf = *(const f16x8*)(Br + kk*32);
            acc = __builtin_amdgcn_mfma_f32_16x16x32_f16(af, bf, acc, 0, 0, 0);
        }
    }
    int wsel = (jt & 1) * 16 + c16;
    int kqp = wsel >> 3, jj = wsel & 7;
    #pragma unroll
    for (int reg = 0; reg < 4; ++reg) {
        int i_g = ti*16 + kq*4 + reg;
        int j_g = jt*16 + c16;
        float val = (jt >= ti) ? acc[reg] : 0.f;
        val *= (j_g > i_g) ? 2.f : ((j_g == i_g) ? 1.f : 0.f);
        Mc[(size_t)((pidx*64 + kqp*16 + (kq*4 + reg)) * 8 + jj)] = (_Float16)val;
    }
}

// ---- 3. fused MFMA quadform: out[p,c] = s_p^T M'_c s_p + bias[c] -----------
// BYTE-IDENTICAL to r12/r13.
__global__ __attribute__((amdgpu_flat_work_group_size(512,512), amdgpu_waves_per_eu(2,4)))
void fusedqf(const _Float16* __restrict__ sF,
             const _Float16* __restrict__ Mp,
             const float* __restrict__ bias,
             float* __restrict__ out) {
    extern __shared__ _Float16 Mlds[];      // 36864 halves = 72 KB
    const int id   = blockIdx.x;
    const int xcd  = id & 7;
    const int g    = id >> 3;
    const int c    = g >> 3;
    const int tile = (g & 7) * 8 + xcd;
    const int tid  = threadIdx.x;
    const int lane = tid & 63;
    const int wv   = tid >> 6;
    const int prow = lane & 15, kq = lane >> 4;
    const int tp0  = tile*32 + wv*4;        // base ptile (of 16 patches)

    // async stage M' (9 x 1KB chunks per wave, zero VGPR cost)
    const _Float16* Msrc = Mp + (size_t)c * MPACK;
    #pragma unroll
    for (int it = 0; it < 9; ++it) {
        int off = (wv*9 + it) * 512;
        gload_lds16(Msrc + off + lane*8, Mlds + off);
    }

    // pass-A B fragments (ks 0..3), overlap with the LDS DMA
    f16x8 bfrag[4][4];
    #pragma unroll
    for (int pt = 0; pt < 4; ++pt) {
        const f16x8* src = (const f16x8*)sF + (size_t)(tp0 + pt)*512 + lane;
        #pragma unroll
        for (int ks = 0; ks < 4; ++ks)
            bfrag[pt][ks] = src[ks*64];
    }

    __syncthreads();   // drains DMA (vmcnt) + joins waves

    const _Float16* fold0 = sF + ((size_t)tp0*512 + (kq>>1)*16 + prow)*8 + (kq&1)*4;
    float o0 = 0.f, o1 = 0.f, o2 = 0.f, o3 = 0.f;
    int pidx = 0;

    f16x4 svn[4];
    #pragma unroll
    for (int pt = 0; pt < 4; ++pt)
        svn[pt] = *(const f16x4*)(fold0 + pt*4096);

    // ---- pass A: t = 0..7 (runtime), ks in [t>>1, 4) ----
    #pragma unroll 1
    for (int t = 0; t < 8; ++t) {
        const int h = t >> 1;
        f16x4 svc[4];
        #pragma unroll
        for (int pt = 0; pt < 4; ++pt) svc[pt] = svn[pt];
        #pragma unroll
        for (int pt = 0; pt < 4; ++pt)
            svn[pt] = *(const f16x4*)(fold0 + pt*4096 + (t+1)*256);

        f32x4 a0 = {0,0,0,0}, a1 = {0,0,0,0}, a2 = {0,0,0,0}, a3 = {0,0,0,0};
        __builtin_amdgcn_s_setprio(1);
        #pragma unroll
        for (int ks = 0; ks < 4; ++ks) {
            if (ks >= h) {                               // wave-uniform
                f16x8 m = *(const f16x8*)(Mlds + (size_t)pidx*512 + lane*8);
                a0 = __builtin_amdgcn_mfma_f32_16x16x32_f16(m, bfrag[0][ks], a0, 0, 0, 0);
                a1 = __builtin_amdgcn_mfma_f32_16x16x32_f16(m, bfrag[1][ks], a1, 0, 0, 0);
                a2 = __builtin_amdgcn_mfma_f32_16x16x32_f16(m, bfrag[2][ks], a2, 0, 0, 0);
                a3 = __builtin_amdgcn_mfma_f32_16x16x32_f16(m, bfrag[3][ks], a3, 0, 0, 0);
                ++pidx;
            }
        }
        __builtin_amdgcn_s_setprio(0);
        pidx += 4;   // skip this t's pass-B pairs (ks 4..7)

        o0 = fold4(svc[0], a0, o0);
        o1 = fold4(svc[1], a1, o1);
        o2 = fold4(svc[2], a2, o2);
        o3 = fold4(svc[3], a3, o3);
    }

    // ---- pass B: load ks 4..7 fragments, t = 0..15 (runtime) ----
    #pragma unroll
    for (int pt = 0; pt < 4; ++pt) {
        const f16x8* src = (const f16x8*)sF + (size_t)(tp0 + pt)*512 + lane;
        #pragma unroll
        for (int ks = 0; ks < 4; ++ks)
            bfrag[pt][ks] = src[(ks+4)*64];
    }

    pidx = 0;
    #pragma unroll
    for (int pt = 0; pt < 4; ++pt)
        svn[pt] = *(const f16x4*)(fold0 + pt*4096);

    #pragma unroll 1
    for (int t = 0; t < 16; ++t) {
        const int h = t >> 1;
        pidx += (h < 4) ? (4 - h) : 0;   // skip this t's pass-A pairs
        f16x4 svc[4];
        #pragma unroll
        for (int pt = 0; pt < 4; ++pt) svc[pt] = svn[pt];
        if (t < 15) {
            #pragma unroll
            for (int pt = 0; pt < 4; ++pt)
                svn[pt] = *(const f16x4*)(fold0 + pt*4096 + (t+1)*256);
        }

        f32x4 a0 = {0,0,0,0}, a1 = {0,0,0,0}, a2 = {0,0,0,0}, a3 = {0,0,0,0};
        __builtin_amdgcn_s_setprio(1);
        #pragma unroll
        for (int ks = 4; ks < 8; ++ks) {
            if (ks >= h) {                               // wave-uniform
                f16x8 m = *(const f16x8*)(Mlds + (size_t)pidx*512 + lane*8);
                a0 = __builtin_amdgcn_mfma_f32_16x16x32_f16(m, bfrag[0][ks-4], a0, 0, 0, 0);
                a1 = __builtin_amdgcn_mfma_f32_16x16x32_f16(m, bfrag[1][ks-4], a1, 0, 0, 0);
                a2 = __builtin_amdgcn_mfma_f32_16x16x32_f16(m, bfrag[2][ks-4], a2, 0, 0, 0);
                a3 = __builtin_amdgcn_mfma_f32_16x16x32_f16(m, bfrag[3][ks-4], a3, 0, 0, 0);
                ++pidx;
            }
        }
        __builtin_amdgcn_s_setprio(0);

        o0 = fold4(svc[0], a0, o0);
        o1 = fold4(svc[1], a1, o1);
        o2 = fold4(svc[2], a2, o2);
        o3 = fold4(svc[3], a3, o3);
    }

    float ov[4] = {o0, o1, o2, o3};
    float bc = bias[c];
    #pragma unroll
    for (int pt = 0; pt < 4; ++pt) {
        float v = ov[pt];
        v += __shfl_xor(v, 16, 64);
        v += __shfl_xor(v, 32, 64);
        if (kq == 0) {
            int p = (tp0 + pt)*16 + prow;
            if (p < NPATCH) {
                int b = p / (OH*OW); int r2 = p % (OH*OW);
                int oi = r2 / OW, oj = r2 % OW;
                out[(((size_t)(b*COUT + c))*OH + oi)*OW + oj] = v + bc;
            }
        }
    }
}

extern "C" void kernel_launch(void* const* d_in, const int* in_sizes, int n_in,
                              void* d_out, int out_size, void* d_ws, size_t ws_size,
                              hipStream_t stream) {
    const float* x    = (const float*)d_in[0];
    const float* w    = (const float*)d_in[1];
    const float* bias = (const float*)d_in[2];
    float* out = (float*)d_out;

    const size_t OFF_AT  = 0;                       // 8*256*512*2 = 2,097,152
    const size_t OFF_BT  = OFF_AT + 2097152;        // 2,097,152
    const size_t OFF_MP  = OFF_BT + 2097152;        // 8*36864*2 = 589,824
    const size_t OFF_SF  = OFF_MP + 589824;         // 2048*512*16 = 16,777,216
    const size_t TOTAL   = OFF_SF + 16777216;
    if (ws_size < TOTAL) return;

    char* ws = (char*)d_ws;
    _Float16* At = (_Float16*)(ws + OFF_AT);
    _Float16* Bt = (_Float16*)(ws + OFF_BT);
    _Float16* Mp = (_Float16*)(ws + OFF_MP);
    _Float16* sF = (_Float16*)(ws + OFF_SF);

    wext<<<NWBLK + NPTILE, 256, 0, stream>>>(w, At, Bt, x, sF);
    build_Mp<<<dim3(4, 16, COUT), 256, 0, stream>>>(At, Bt, Mp);
    fusedqf<<<NTILE*COUT, 512, MPACK*sizeof(_Float16), stream>>>(sF, Mp, bias, out);
}